// Round 7
// baseline (13585.753 us; speedup 1.0000x reference)
//
#include <hip/hip_runtime.h>
#include <hip/hip_bf16.h>
#include <stdint.h>

typedef unsigned short u16;
typedef __bf16 bf16x8v __attribute__((ext_vector_type(8)));
typedef float f32x4 __attribute__((ext_vector_type(4)));

#define B_ 16
#define S_ 128
#define T1_ 127
#define E_ 512
#define H_ 1024
#define H4_ 4096
#define V_ 32000
#define NEGBIG -1e10f
#define NBLK 512

__device__ __forceinline__ u16 f2bf(float f) {
    union { float f; unsigned u; } v; v.f = f;
    unsigned u = v.u;
    unsigned r = (u + 0x7fffu + ((u >> 16) & 1u)) >> 16;
    return (u16)r;
}
__device__ __forceinline__ float bf2f(u16 h) {
    union { unsigned u; float f; } v; v.u = ((unsigned)h) << 16;
    return v.f;
}
__device__ __forceinline__ float sigm(float x) { return 1.f / (1.f + expf(-x)); }
__device__ __forceinline__ float dot4(float4 a, float4 b) {
    return a.x * b.x + a.y * b.y + a.z * b.z + a.w * b.w;
}

// Cross-block publish: device-scope RMW (coherent across XCDs). Proven r6.
__device__ __forceinline__ void pubf(float* p, float v) { atomicExch(p, v); }

// ---- grid barrier v3: single monotone counter ----
// arrive: one atomicAdd per block. wait: relaxed agent-scope atomic load
// (sc1, L2-bypass, NO acquire fence / buffer_inv). No release phase.
__device__ __forceinline__ void gbar(int* cnt, int target) {
    asm volatile("s_waitcnt vmcnt(0) lgkmcnt(0)" ::: "memory");
    __syncthreads();
    if (threadIdx.x == 0) {
        atomicAdd(cnt, 1);
        while (__hip_atomic_load(cnt, __ATOMIC_RELAXED, __HIP_MEMORY_SCOPE_AGENT) <
               target)
            __builtin_amdgcn_s_sleep(4);
    }
    __syncthreads();
}

// ---------------- converts / gathers (verified) ----------------

__global__ __launch_bounds__(256) void f32_to_bf16_k(const float* __restrict__ src,
                                                     u16* __restrict__ dst, int n4) {
    int idx = blockIdx.x * 256 + threadIdx.x;
    if (idx >= n4) return;
    float4 v = ((const float4*)src)[idx];
    unsigned lo = (unsigned)f2bf(v.x) | ((unsigned)f2bf(v.y) << 16);
    unsigned hi = (unsigned)f2bf(v.z) | ((unsigned)f2bf(v.w) << 16);
    uint2 pk; pk.x = lo; pk.y = hi;
    *(uint2*)(dst + (size_t)idx * 4) = pk;
}

__global__ __launch_bounds__(128) void split3_rows_k(const float* __restrict__ src,
                                                     int srcStride,
                                                     u16* __restrict__ dst, int nrows,
                                                     int offH2, int offLo) {
    int j = blockIdx.x;
    if (j >= nrows) return;
    int tid = threadIdx.x;
    float4 v = *(const float4*)(src + (size_t)j * srcStride + tid * 4);
    u16 h0 = f2bf(v.x), h1 = f2bf(v.y), h2 = f2bf(v.z), h3 = f2bf(v.w);
    u16 l0 = f2bf(v.x - bf2f(h0)), l1 = f2bf(v.y - bf2f(h1));
    u16 l2 = f2bf(v.z - bf2f(h2)), l3 = f2bf(v.w - bf2f(h3));
    uint2 ph; ph.x = (unsigned)h0 | ((unsigned)h1 << 16); ph.y = (unsigned)h2 | ((unsigned)h3 << 16);
    uint2 pl; pl.x = (unsigned)l0 | ((unsigned)l1 << 16); pl.y = (unsigned)l2 | ((unsigned)l3 << 16);
    u16* base = dst + (size_t)j * 1536 + tid * 4;
    *(uint2*)(base) = ph;
    *(uint2*)(base + offH2) = ph;
    *(uint2*)(base + offLo) = pl;
}

__global__ __launch_bounds__(128) void gather_split_k(const int* __restrict__ toks,
                                                      const float* __restrict__ emb,
                                                      u16* __restrict__ A, int nrows) {
    int m = blockIdx.x;
    if (m >= nrows) return;
    int tIdx = m >> 4, b = m & 15;
    int tok = toks[b * 128 + tIdx];
    int tid = threadIdx.x;
    float4 v = *(const float4*)(emb + (size_t)tok * E_ + tid * 4);
    u16 h0 = f2bf(v.x), h1 = f2bf(v.y), h2 = f2bf(v.z), h3 = f2bf(v.w);
    u16 l0 = f2bf(v.x - bf2f(h0)), l1 = f2bf(v.y - bf2f(h1));
    u16 l2 = f2bf(v.z - bf2f(h2)), l3 = f2bf(v.w - bf2f(h3));
    uint2 ph; ph.x = (unsigned)h0 | ((unsigned)h1 << 16); ph.y = (unsigned)h2 | ((unsigned)h3 << 16);
    uint2 pl; pl.x = (unsigned)l0 | ((unsigned)l1 << 16); pl.y = (unsigned)l2 | ((unsigned)l3 << 16);
    u16* base = A + (size_t)m * 1536 + tid * 4;
    *(uint2*)(base) = ph;
    *(uint2*)(base + 512) = ph;
    *(uint2*)(base + 1024) = pl;
}

// zero state (h0|c|a0 = 48K floats) + barrier counters (256 ints) + mask2
__global__ __launch_bounds__(256) void init_k(float* __restrict__ zero1,
                                              int* __restrict__ cnts,
                                              const int* __restrict__ mask,
                                              int* __restrict__ mask2) {
    int idx = blockIdx.x * 256 + threadIdx.x;
    float4 z = {0.f, 0.f, 0.f, 0.f};
    if (idx < 12288) ((float4*)zero1)[idx] = z;
    if (idx < 64) { int4 zi = {0, 0, 0, 0}; ((int4*)cnts)[idx] = zi; }
    if (blockIdx.x == 0 && threadIdx.x < 16) {
        int b = threadIdx.x;
        int first0 = 128;
        for (int s = 0; s < 128; ++s) {
            if (mask[b * 128 + s] == 0) { first0 = s; break; }
        }
        if (first0 == 128) first0 = 0;
        int len = first0 - 1;
        int ix = (len < 0) ? 127 : len;
        for (int s = 0; s < 128; ++s) mask2[b * 128 + s] = mask[b * 128 + s];
        mask2[b * 128 + ix] = 0;
    }
}

// ---------------- bf16 MFMA GEMM (verified) ----------------

#define GLD_LDS(g, l) \
    __builtin_amdgcn_global_load_lds((const __attribute__((address_space(1))) void*)(g), \
                                     (__attribute__((address_space(3))) void*)(l), 16, 0, 0)

template <int MODE>
__global__ __launch_bounds__(256) void gemm_bt(const u16* __restrict__ A,
                                               const u16* __restrict__ Bt,
                                               float* __restrict__ C,
                                               const float* __restrict__ bias1,
                                               const float* __restrict__ bias2,
                                               int M, int N, int K) {
    __shared__ u16 As[128 * 32];
    __shared__ u16 Bs[128 * 32];
    const int tid = threadIdx.x;
    const int bm = blockIdx.x, bn = blockIdx.y;
    const int lane = tid & 63, w = tid >> 6;
    const int wm = (w >> 1) * 64, wn = (w & 1) * 64;
    f32x4 acc[4][4] = {};

    const int r0 = tid >> 2;
    const int c0 = (tid & 3) * 8;
    const u16* ga0 = A + (size_t)(bm * 128 + r0) * K + c0;
    const u16* ga1 = A + (size_t)(bm * 128 + 64 + r0) * K + c0;
    const u16* gb0 = Bt + (size_t)(bn * 128 + r0) * K + c0;
    const u16* gb1 = Bt + (size_t)(bn * 128 + 64 + r0) * K + c0;
    u16* lA0 = As + tid * 8;
    u16* lA1 = As + 2048 + tid * 8;
    u16* lB0 = Bs + tid * 8;
    u16* lB1 = Bs + 2048 + tid * 8;

    const int fl = lane & 15, kg = lane >> 4;

    for (int k0 = 0; k0 < K; k0 += 32) {
        __syncthreads();
        GLD_LDS(ga0 + k0, lA0);
        GLD_LDS(ga1 + k0, lA1);
        GLD_LDS(gb0 + k0, lB0);
        GLD_LDS(gb1 + k0, lB1);
        __syncthreads();
        bf16x8v af[4], bfv[4];
#pragma unroll
        for (int i = 0; i < 4; ++i)
            af[i] = *(const bf16x8v*)(As + (wm + i * 16 + fl) * 32 + kg * 8);
#pragma unroll
        for (int j = 0; j < 4; ++j)
            bfv[j] = *(const bf16x8v*)(Bs + (wn + j * 16 + fl) * 32 + kg * 8);
#pragma unroll
        for (int i = 0; i < 4; ++i)
#pragma unroll
            for (int j = 0; j < 4; ++j)
                acc[i][j] = __builtin_amdgcn_mfma_f32_16x16x32_bf16(af[i], bfv[j], acc[i][j], 0, 0, 0);
    }

    const int coll = lane & 15;
    const int rowb = (lane >> 4) * 4;
#pragma unroll
    for (int i = 0; i < 4; ++i) {
#pragma unroll
        for (int j = 0; j < 4; ++j) {
#pragma unroll
            for (int r = 0; r < 4; ++r) {
                int m = bm * 128 + wm + i * 16 + rowb + r;
                int n = bn * 128 + wn + j * 16 + coll;
                float v = acc[i][j][r];
                if (MODE == 0) {
                    if (m < M) C[(size_t)m * N + n] = v + bias1[n] + bias2[n];
                } else {
                    int tt = m >> 4, bb = m & 15;
                    if (tt < T1_) C[((size_t)bb * T1_ + tt) * V_ + n] = v + bias1[n];
                }
            }
        }
    }
}

// ---------------- persistent encoder ----------------

__global__ __launch_bounds__(256, 2) void enc_persist(
    const float* __restrict__ pre, const float* __restrict__ Whh,
    const float* __restrict__ h0zero, float* __restrict__ c,
    float* __restrict__ enc_out, int* cnt) {
    __shared__ float4 red4[4 * 64 * 17];
    __shared__ float zred[256];
    const int bk = blockIdx.x;
    const int tid = threadIdx.x;
    const int wv = tid >> 6, lane = tid & 63;
    const int k0 = wv * 256 + lane * 4;

    float4 wr[2][4];
#pragma unroll
    for (int dd = 0; dd < 2; ++dd) {
        int d = (bk << 1) + dd;
#pragma unroll
        for (int g = 0; g < 4; ++g)
            wr[dd][g] = *(const float4*)(Whh + (size_t)(g * 1024 + d) * H_ + k0);
    }

    int ep = 0;
    for (int t = 0; t < 128; ++t) {
        const float* xsrc;
        size_t xstr;
        if (t == 0) { xsrc = h0zero; xstr = H_; }
        else { xsrc = enc_out + (size_t)(t - 1) * H_; xstr = (size_t)128 * H_; }

        // prefetch gate pre-activations early (hide scattered HBM latency)
        float prz[8];
        if (tid < 16) {
            const float* pb = pre + (size_t)(t * 16 + tid) * H4_ + (bk << 1);
#pragma unroll
            for (int g = 0; g < 4; ++g) {
                prz[g * 2 + 0] = pb[g * 1024 + 0];
                prz[g * 2 + 1] = pb[g * 1024 + 1];
            }
        }

        for (int dd = 0; dd < 2; ++dd) {
            const int d = (bk << 1) + dd;
            float4 part[16];
#pragma unroll
            for (int b = 0; b < 16; ++b) {
                float4 hv = *(const float4*)(xsrc + (size_t)b * xstr + k0);
                part[b].x = dot4(wr[dd][0], hv);
                part[b].y = dot4(wr[dd][1], hv);
                part[b].z = dot4(wr[dd][2], hv);
                part[b].w = dot4(wr[dd][3], hv);
            }
#pragma unroll
            for (int b = 0; b < 16; ++b) red4[(wv * 64 + lane) * 17 + b] = part[b];
            __syncthreads();
            {
                int v = tid & 63, wq = tid >> 6;
                const float* rf = (const float*)red4;
                float s = 0.f;
#pragma unroll 8
                for (int l = 0; l < 64; ++l) s += rf[(wq * 64 + l) * 68 + v];
                zred[wq * 64 + v] = s;
            }
            __syncthreads();
            if (tid < 16) {
                int b = tid;
                float zz[4];
#pragma unroll
                for (int g = 0; g < 4; ++g) {
                    float s = zred[b * 4 + g] + zred[64 + b * 4 + g] +
                              zred[128 + b * 4 + g] + zred[192 + b * 4 + g];
                    zz[g] = s + prz[g * 2 + dd];
                }
                float co = c[b * H_ + d];
                float c2 = sigm(zz[1]) * co + sigm(zz[0]) * tanhf(zz[2]);
                float h2 = sigm(zz[3]) * tanhf(c2);
                c[b * H_ + d] = c2;
                pubf(&enc_out[((size_t)b * 128 + t) * H_ + d], h2);
            }
            __syncthreads();
        }
        ++ep;
        gbar(cnt, ep * NBLK);
    }
}

// ---------------- persistent decoder: 3 phases/step ----------------

__global__ __launch_bounds__(256, 2) void dec_persist(
    const float* __restrict__ pre, const float* __restrict__ Whh,
    const float* __restrict__ WihFull, const float* __restrict__ attn_W,
    const float* __restrict__ attn_b, const float* __restrict__ enc_out,
    float* __restrict__ h_ring, float* __restrict__ a_ring,
    float* __restrict__ ct_ring, const float* __restrict__ a0zero,
    float* __restrict__ c, const int* __restrict__ mask2,
    u16* __restrict__ a2bf, int* cnt) {
    __shared__ float4 red4[4 * 64 * 17];
    __shared__ float zred[256];
    __shared__ float hq[1024];
    __shared__ float ps[128];
    __shared__ float red[2];
    const int bk = blockIdx.x;
    const int tid = threadIdx.x;
    const int wv = tid >> 6, lane = tid & 63;
    const int kq = (wv & 1) * 512 + lane * 8;
    const bool isA = wv >= 2;
    const bool isH = wv >= 2;

    float4 wr[2][4][2];
#pragma unroll
    for (int dd = 0; dd < 2; ++dd) {
        int d = (bk << 1) + dd;
#pragma unroll
        for (int g = 0; g < 4; ++g) {
            int j = g * 1024 + d;
            const float* wsrc = isA ? (WihFull + (size_t)j * 1536 + 512 + kq)
                                    : (Whh + (size_t)j * H_ + kq);
            wr[dd][g][0] = *(const float4*)(wsrc);
            wr[dd][g][1] = *(const float4*)(wsrc + 4);
        }
    }
    float4 wa2[2][2];
#pragma unroll
    for (int dd = 0; dd < 2; ++dd) {
        int d = (bk << 1) + dd;
        const float* wsrc = attn_W + (size_t)d * 2048 + (isH ? 1024 : 0) + kq;
        wa2[dd][0] = *(const float4*)(wsrc);
        wa2[dd][1] = *(const float4*)(wsrc + 4);
    }

    int ep = 0;
    for (int t = 0; t < T1_; ++t) {
        const float* hsrc;
        size_t hstr;
        if (t == 0) { hsrc = enc_out + (size_t)127 * H_; hstr = (size_t)128 * H_; }
        else { hsrc = h_ring + (size_t)(t - 1) * B_ * H_; hstr = H_; }
        const float* asrc = (t == 0) ? a0zero : (a_ring + (size_t)(t - 1) * B_ * H_);
        float* hcur = h_ring + (size_t)t * B_ * H_;
        float* ctcur = ct_ring + (size_t)t * B_ * H_;
        float* acur = a_ring + (size_t)t * B_ * H_;

        // prefetch gate pre-activations
        float prz[8];
        if (tid < 16) {
            const float* pb = pre + (size_t)(t * 16 + tid) * H4_ + (bk << 1);
#pragma unroll
            for (int g = 0; g < 4; ++g) {
                prz[g * 2 + 0] = pb[g * 1024 + 0];
                prz[g * 2 + 1] = pb[g * 1024 + 1];
            }
        }

        // ---- phase 1: LSTM for my 2 d ----
        const float* xsrc1 = isA ? asrc : hsrc;
        const size_t xstr1 = isA ? (size_t)H_ : hstr;
        for (int dd = 0; dd < 2; ++dd) {
            const int d = (bk << 1) + dd;
            float4 part[16];
#pragma unroll
            for (int b = 0; b < 16; ++b) {
                float4 x0 = *(const float4*)(xsrc1 + (size_t)b * xstr1 + kq);
                float4 x1 = *(const float4*)(xsrc1 + (size_t)b * xstr1 + kq + 4);
                part[b].x = dot4(wr[dd][0][0], x0) + dot4(wr[dd][0][1], x1);
                part[b].y = dot4(wr[dd][1][0], x0) + dot4(wr[dd][1][1], x1);
                part[b].z = dot4(wr[dd][2][0], x0) + dot4(wr[dd][2][1], x1);
                part[b].w = dot4(wr[dd][3][0], x0) + dot4(wr[dd][3][1], x1);
            }
#pragma unroll
            for (int b = 0; b < 16; ++b) red4[(wv * 64 + lane) * 17 + b] = part[b];
            __syncthreads();
            {
                int v = tid & 63, wq = tid >> 6;
                const float* rf = (const float*)red4;
                float s = 0.f;
#pragma unroll 8
                for (int l = 0; l < 64; ++l) s += rf[(wq * 64 + l) * 68 + v];
                zred[wq * 64 + v] = s;
            }
            __syncthreads();
            if (tid < 16) {
                int b = tid;
                float zz[4];
#pragma unroll
                for (int g = 0; g < 4; ++g) {
                    float s = zred[b * 4 + g] + zred[64 + b * 4 + g] +
                              zred[128 + b * 4 + g] + zred[192 + b * 4 + g];
                    zz[g] = s + prz[g * 2 + dd];
                }
                float co = c[b * H_ + d];
                float c2 = sigm(zz[1]) * co + sigm(zz[0]) * tanhf(zz[2]);
                float h2 = sigm(zz[3]) * tanhf(c2);
                c[b * H_ + d] = c2;
                pubf(&hcur[b * H_ + d], h2);
            }
            __syncthreads();
        }
        ++ep;
        gbar(cnt, ep * NBLK);

        // ---- phase 2: attention (blocks 0..15) ----
        if (bk < 16) {
            int b = bk;
            *(float4*)(hq + tid * 4) = *(const float4*)(hcur + b * H_ + tid * 4);
            __syncthreads();
            int s = tid >> 1, hf = tid & 1;
            const float* er = enc_out + ((size_t)b * 128 + s) * H_ + hf * 512;
            const float* hr = hq + hf * 512;
            float sc = 0.f;
            for (int k = 0; k < 512; k += 4) {
                float4 e = *(const float4*)(er + k);
                sc += e.x * hr[k] + e.y * hr[k + 1] + e.z * hr[k + 2] + e.w * hr[k + 3];
            }
            sc += __shfl_xor(sc, 1);
            if (hf == 0) ps[s] = (mask2[b * 128 + s] == 1) ? NEGBIG : sc;
            __syncthreads();
            if (tid < 64) {
                float m2 = fmaxf(ps[tid], ps[tid + 64]);
                for (int off = 32; off; off >>= 1) m2 = fmaxf(m2, __shfl_xor(m2, off));
                if (tid == 0) red[0] = m2;
            }
            __syncthreads();
            if (tid < 128) ps[tid] = expf(ps[tid] - red[0]);
            __syncthreads();
            if (tid < 64) {
                float s2 = ps[tid] + ps[tid + 64];
                for (int off = 32; off; off >>= 1) s2 += __shfl_xor(s2, off);
                if (tid == 0) red[1] = 1.f / s2;
            }
            __syncthreads();
            float inv = red[1];
            int d0 = tid * 4;
            float4 av = {0.f, 0.f, 0.f, 0.f};
            for (int s2 = 0; s2 < 128; ++s2) {
                float p = ps[s2] * inv;
                float4 e = *(const float4*)(enc_out + ((size_t)b * 128 + s2) * H_ + d0);
                av.x += p * e.x; av.y += p * e.y; av.z += p * e.z; av.w += p * e.w;
            }
            pubf(&ctcur[b * H_ + d0 + 0], av.x);
            pubf(&ctcur[b * H_ + d0 + 1], av.y);
            pubf(&ctcur[b * H_ + d0 + 2], av.z);
            pubf(&ctcur[b * H_ + d0 + 3], av.w);
        }
        ++ep;
        gbar(cnt, ep * NBLK);

        // ---- phase 3: a2 for my 2 d ----
        const float* xsrc3 = isH ? hcur : ctcur;
        for (int dd = 0; dd < 2; ++dd) {
            const int d = (bk << 1) + dd;
            float partA[16];
#pragma unroll
            for (int b = 0; b < 16; ++b) {
                float4 x0 = *(const float4*)(xsrc3 + b * H_ + kq);
                float4 x1 = *(const float4*)(xsrc3 + b * H_ + kq + 4);
                partA[b] = dot4(wa2[dd][0], x0) + dot4(wa2[dd][1], x1);
            }
#pragma unroll
            for (int q = 0; q < 4; ++q)
                red4[(wv * 64 + lane) * 17 + q] =
                    make_float4(partA[q * 4], partA[q * 4 + 1], partA[q * 4 + 2], partA[q * 4 + 3]);
            __syncthreads();
            if (tid < 64) {
                int v = tid & 15, wq = tid >> 4;
                const float* rf = (const float*)red4;
                float s = 0.f;
#pragma unroll 8
                for (int l = 0; l < 64; ++l) s += rf[(wq * 64 + l) * 68 + v];
                zred[wq * 16 + v] = s;
            }
            __syncthreads();
            if (tid < 16) {
                int b = tid;
                float v = zred[b] + zred[16 + b] + zred[32 + b] + zred[48 + b] + attn_b[d];
                v = tanhf(v);
                pubf(&acur[b * H_ + d], v);
                a2bf[((size_t)(t * 16 + b)) * H_ + d] = f2bf(v);
            }
            __syncthreads();
        }
        ++ep;
        gbar(cnt, ep * NBLK);
    }
}

// ---------------- orchestration ----------------

extern "C" void kernel_launch(void* const* d_in, const int* in_sizes, int n_in,
                              void* d_out, int out_size, void* d_ws, size_t ws_size,
                              hipStream_t stream) {
    const int* in_tok = (const int*)d_in[0];
    const int* out_tok = (const int*)d_in[1];
    const int* mask = (const int*)d_in[2];
    const float* emb_in = (const float*)d_in[3];
    const float* emb_out = (const float*)d_in[4];
    const float* enc_Wih = (const float*)d_in[5];
    const float* enc_Whh = (const float*)d_in[6];
    const float* enc_bih = (const float*)d_in[7];
    const float* enc_bhh = (const float*)d_in[8];
    const float* dec_Wih = (const float*)d_in[9];
    const float* dec_Whh = (const float*)d_in[10];
    const float* dec_bih = (const float*)d_in[11];
    const float* dec_bhh = (const float*)d_in[12];
    const float* attn_W = (const float*)d_in[13];
    const float* attn_b = (const float*)d_in[14];
    const float* out_W = (const float*)d_in[15];
    const float* out_b = (const float*)d_in[16];
    float* out = (float*)d_out;

    char* p = (char*)d_ws;
    auto alloc = [&](size_t bytes) {
        char* r = p;
        p += (bytes + 255) & ~(size_t)255;
        return r;
    };
    u16* A_enc3 = (u16*)alloc((size_t)2048 * 1536 * 2);
    u16* A_dec3 = (u16*)alloc((size_t)2048 * 1536 * 2);
    u16* W_e3 = (u16*)alloc((size_t)4096 * 1536 * 2);
    u16* W_d3 = (u16*)alloc((size_t)4096 * 1536 * 2);
    u16* Wo = (u16*)alloc((size_t)32000 * 1024 * 2);
    float* enc_pre = (float*)alloc((size_t)2048 * 4096 * 4);
    float* dec_pre = (float*)alloc((size_t)2048 * 4096 * 4);
    float* enc_out = (float*)alloc((size_t)16 * 128 * 1024 * 4);
    u16* a2bf = (u16*)alloc((size_t)2048 * 1024 * 2);
    float* h0 = (float*)alloc(16 * 1024 * 4);
    float* c = (float*)alloc(16 * 1024 * 4);
    float* a0 = (float*)alloc(16 * 1024 * 4);
    int* cnts = (int*)alloc(256 * 4);  // cnt_e at +0, cnt_d at +64 (sep lines)
    int* mask2 = (int*)alloc(16 * 128 * 4);

    float* h_ring = (float*)A_enc3;
    float* a_ring = h_ring + (size_t)128 * B_ * H_;
    float* ct_ring = a_ring + (size_t)128 * B_ * H_;

    init_k<<<48, 256, 0, stream>>>(h0, cnts, mask, mask2);

    split3_rows_k<<<4096, 128, 0, stream>>>(enc_Wih, 512, W_e3, 4096, 1024, 512);
    split3_rows_k<<<4096, 128, 0, stream>>>(dec_Wih, 1536, W_d3, 4096, 1024, 512);
    f32_to_bf16_k<<<32000, 256, 0, stream>>>(out_W, Wo, 32000 * 1024 / 4);
    gather_split_k<<<2048, 128, 0, stream>>>(in_tok, emb_in, A_enc3, 2048);
    gather_split_k<<<2032, 128, 0, stream>>>(out_tok, emb_out, A_dec3, 2032);

    gemm_bt<0><<<dim3(16, 32), 256, 0, stream>>>(A_enc3, W_e3, enc_pre, enc_bih, enc_bhh,
                                                 2048, 4096, 1536);
    gemm_bt<0><<<dim3(16, 32), 256, 0, stream>>>(A_dec3, W_d3, dec_pre, dec_bih, dec_bhh,
                                                 2048, 4096, 1536);

    enc_persist<<<512, 256, 0, stream>>>(enc_pre, enc_Whh, h0, c, enc_out, cnts);

    dec_persist<<<512, 256, 0, stream>>>(dec_pre, dec_Whh, dec_Wih, attn_W, attn_b,
                                         enc_out, h_ring, a_ring, ct_ring, a0, c,
                                         mask2, a2bf, cnts + 64);

    gemm_bt<1><<<dim3(16, 250), 256, 0, stream>>>(a2bf, Wo, out, out_b, nullptr,
                                                  2048, 32000, 1024);
}

// Round 8
// 8343.342 us; speedup vs baseline: 1.6283x; 1.6283x over previous
//
#include <hip/hip_runtime.h>
#include <hip/hip_bf16.h>
#include <stdint.h>

typedef unsigned short u16;
typedef unsigned long long u64;
typedef __bf16 bf16x8v __attribute__((ext_vector_type(8)));
typedef float f32x4 __attribute__((ext_vector_type(4)));

#define B_ 16
#define S_ 128
#define T1_ 127
#define E_ 512
#define H_ 1024
#define H4_ 4096
#define V_ 32000
#define NEGBIG -1e10f
#define NBLK 512

__device__ __forceinline__ u16 f2bf(float f) {
    union { float f; unsigned u; } v; v.f = f;
    unsigned u = v.u;
    unsigned r = (u + 0x7fffu + ((u >> 16) & 1u)) >> 16;
    return (u16)r;
}
__device__ __forceinline__ float bf2f(u16 h) {
    union { unsigned u; float f; } v; v.u = ((unsigned)h) << 16;
    return v.f;
}
__device__ __forceinline__ float sigm(float x) { return 1.f / (1.f + expf(-x)); }
__device__ __forceinline__ float dot4(float4 a, float4 b) {
    return a.x * b.x + a.y * b.y + a.z * b.z + a.w * b.w;
}
__device__ __forceinline__ void pub2(float* p, float v0, float v1) {
    union { float f[2]; u64 u; } pk;
    pk.f[0] = v0; pk.f[1] = v1;
    atomicExch((u64*)p, pk.u);
}

// ---- grid barrier v4: tournament, <=8 RMWs/pollers per cache line ----
// bar layout (ints, 64B stride units of 16):
//   c1[64]  at 0      (8 arrivals each)
//   c2[8]   at 1024   (8 arrivals each, from c1 winners)
//   c3      at 1152   (8 arrivals, from c2 winners)
//   rel2[8] at 1216   (written by final winner; polled by 8 relay blocks each)
//   rel1[64] at 1344  (written by relay blocks bk<64; polled by <=7 blocks each)
__device__ __forceinline__ void gbar(int* bar, int ep, int bk) {
    asm volatile("s_waitcnt vmcnt(0) lgkmcnt(0)" ::: "memory");
    __syncthreads();
    if (threadIdx.x == 0) {
        const int g1 = bk & 63, g2 = g1 >> 3;
        int old = atomicAdd(&bar[g1 * 16], 1);
        if (old == ep * 8 - 1) {
            int old2 = atomicAdd(&bar[1024 + g2 * 16], 1);
            if (old2 == ep * 8 - 1) {
                int old3 = atomicAdd(&bar[1152], 1);
                if (old3 == ep * 8 - 1) {
#pragma unroll
                    for (int j = 0; j < 8; ++j) atomicExch(&bar[1216 + j * 16], ep);
                }
            }
        }
        if (bk < 64) {
            while (__hip_atomic_load(&bar[1216 + (bk >> 3) * 16], __ATOMIC_RELAXED,
                                     __HIP_MEMORY_SCOPE_AGENT) < ep)
                __builtin_amdgcn_s_sleep(2);
            atomicExch(&bar[1344 + bk * 16], ep);
        } else {
            while (__hip_atomic_load(&bar[1344 + (bk & 63) * 16], __ATOMIC_RELAXED,
                                     __HIP_MEMORY_SCOPE_AGENT) < ep)
                __builtin_amdgcn_s_sleep(2);
        }
    }
    __syncthreads();
}

// ---------------- converts / gathers (verified) ----------------

__global__ __launch_bounds__(256) void f32_to_bf16_k(const float* __restrict__ src,
                                                     u16* __restrict__ dst, int n4) {
    int idx = blockIdx.x * 256 + threadIdx.x;
    if (idx >= n4) return;
    float4 v = ((const float4*)src)[idx];
    unsigned lo = (unsigned)f2bf(v.x) | ((unsigned)f2bf(v.y) << 16);
    unsigned hi = (unsigned)f2bf(v.z) | ((unsigned)f2bf(v.w) << 16);
    uint2 pk; pk.x = lo; pk.y = hi;
    *(uint2*)(dst + (size_t)idx * 4) = pk;
}

__global__ __launch_bounds__(128) void split3_rows_k(const float* __restrict__ src,
                                                     int srcStride,
                                                     u16* __restrict__ dst, int nrows,
                                                     int offH2, int offLo) {
    int j = blockIdx.x;
    if (j >= nrows) return;
    int tid = threadIdx.x;
    float4 v = *(const float4*)(src + (size_t)j * srcStride + tid * 4);
    u16 h0 = f2bf(v.x), h1 = f2bf(v.y), h2 = f2bf(v.z), h3 = f2bf(v.w);
    u16 l0 = f2bf(v.x - bf2f(h0)), l1 = f2bf(v.y - bf2f(h1));
    u16 l2 = f2bf(v.z - bf2f(h2)), l3 = f2bf(v.w - bf2f(h3));
    uint2 ph; ph.x = (unsigned)h0 | ((unsigned)h1 << 16); ph.y = (unsigned)h2 | ((unsigned)h3 << 16);
    uint2 pl; pl.x = (unsigned)l0 | ((unsigned)l1 << 16); pl.y = (unsigned)l2 | ((unsigned)l3 << 16);
    u16* base = dst + (size_t)j * 1536 + tid * 4;
    *(uint2*)(base) = ph;
    *(uint2*)(base + offH2) = ph;
    *(uint2*)(base + offLo) = pl;
}

__global__ __launch_bounds__(128) void gather_split_k(const int* __restrict__ toks,
                                                      const float* __restrict__ emb,
                                                      u16* __restrict__ A, int nrows) {
    int m = blockIdx.x;
    if (m >= nrows) return;
    int tIdx = m >> 4, b = m & 15;
    int tok = toks[b * 128 + tIdx];
    int tid = threadIdx.x;
    float4 v = *(const float4*)(emb + (size_t)tok * E_ + tid * 4);
    u16 h0 = f2bf(v.x), h1 = f2bf(v.y), h2 = f2bf(v.z), h3 = f2bf(v.w);
    u16 l0 = f2bf(v.x - bf2f(h0)), l1 = f2bf(v.y - bf2f(h1));
    u16 l2 = f2bf(v.z - bf2f(h2)), l3 = f2bf(v.w - bf2f(h3));
    uint2 ph; ph.x = (unsigned)h0 | ((unsigned)h1 << 16); ph.y = (unsigned)h2 | ((unsigned)h3 << 16);
    uint2 pl; pl.x = (unsigned)l0 | ((unsigned)l1 << 16); pl.y = (unsigned)l2 | ((unsigned)l3 << 16);
    u16* base = A + (size_t)m * 1536 + tid * 4;
    *(uint2*)(base) = ph;
    *(uint2*)(base + 512) = ph;
    *(uint2*)(base + 1024) = pl;
}

// zero state (h0|c|a0 = 48K floats) + barrier arrays (8192 ints) + mask2
__global__ __launch_bounds__(256) void init_k(float* __restrict__ zero1,
                                              int* __restrict__ zero2,
                                              const int* __restrict__ mask,
                                              int* __restrict__ mask2) {
    int idx = blockIdx.x * 256 + threadIdx.x;
    float4 z = {0.f, 0.f, 0.f, 0.f};
    if (idx < 12288) ((float4*)zero1)[idx] = z;
    if (idx < 2048) { int4 zi = {0, 0, 0, 0}; ((int4*)zero2)[idx] = zi; }
    if (blockIdx.x == 0 && threadIdx.x < 16) {
        int b = threadIdx.x;
        int first0 = 128;
        for (int s = 0; s < 128; ++s) {
            if (mask[b * 128 + s] == 0) { first0 = s; break; }
        }
        if (first0 == 128) first0 = 0;
        int len = first0 - 1;
        int ix = (len < 0) ? 127 : len;
        for (int s = 0; s < 128; ++s) mask2[b * 128 + s] = mask[b * 128 + s];
        mask2[b * 128 + ix] = 0;
    }
}

// ---------------- bf16 MFMA GEMM (verified) ----------------
// MODE 1: logits. MODE 2: pre2 layout [t][d>>1][b][g][d&1].

#define GLD_LDS(g, l) \
    __builtin_amdgcn_global_load_lds((const __attribute__((address_space(1))) void*)(g), \
                                     (__attribute__((address_space(3))) void*)(l), 16, 0, 0)

template <int MODE>
__global__ __launch_bounds__(256) void gemm_bt(const u16* __restrict__ A,
                                               const u16* __restrict__ Bt,
                                               float* __restrict__ C,
                                               const float* __restrict__ bias1,
                                               const float* __restrict__ bias2,
                                               int M, int N, int K) {
    __shared__ u16 As[128 * 32];
    __shared__ u16 Bs[128 * 32];
    const int tid = threadIdx.x;
    const int bm = blockIdx.x, bn = blockIdx.y;
    const int lane = tid & 63, w = tid >> 6;
    const int wm = (w >> 1) * 64, wn = (w & 1) * 64;
    f32x4 acc[4][4] = {};

    const int r0 = tid >> 2;
    const int c0 = (tid & 3) * 8;
    const u16* ga0 = A + (size_t)(bm * 128 + r0) * K + c0;
    const u16* ga1 = A + (size_t)(bm * 128 + 64 + r0) * K + c0;
    const u16* gb0 = Bt + (size_t)(bn * 128 + r0) * K + c0;
    const u16* gb1 = Bt + (size_t)(bn * 128 + 64 + r0) * K + c0;
    u16* lA0 = As + tid * 8;
    u16* lA1 = As + 2048 + tid * 8;
    u16* lB0 = Bs + tid * 8;
    u16* lB1 = Bs + 2048 + tid * 8;

    const int fl = lane & 15, kg = lane >> 4;

    for (int k0 = 0; k0 < K; k0 += 32) {
        __syncthreads();
        GLD_LDS(ga0 + k0, lA0);
        GLD_LDS(ga1 + k0, lA1);
        GLD_LDS(gb0 + k0, lB0);
        GLD_LDS(gb1 + k0, lB1);
        __syncthreads();
        bf16x8v af[4], bfv[4];
#pragma unroll
        for (int i = 0; i < 4; ++i)
            af[i] = *(const bf16x8v*)(As + (wm + i * 16 + fl) * 32 + kg * 8);
#pragma unroll
        for (int j = 0; j < 4; ++j)
            bfv[j] = *(const bf16x8v*)(Bs + (wn + j * 16 + fl) * 32 + kg * 8);
#pragma unroll
        for (int i = 0; i < 4; ++i)
#pragma unroll
            for (int j = 0; j < 4; ++j)
                acc[i][j] = __builtin_amdgcn_mfma_f32_16x16x32_bf16(af[i], bfv[j], acc[i][j], 0, 0, 0);
    }

    const int coll = lane & 15;
    const int rowb = (lane >> 4) * 4;
#pragma unroll
    for (int i = 0; i < 4; ++i) {
#pragma unroll
        for (int j = 0; j < 4; ++j) {
#pragma unroll
            for (int r = 0; r < 4; ++r) {
                int m = bm * 128 + wm + i * 16 + rowb + r;
                int n = bn * 128 + wn + j * 16 + coll;
                float v = acc[i][j][r];
                if (MODE == 1) {
                    int tt = m >> 4, bb = m & 15;
                    if (tt < T1_) C[((size_t)bb * T1_ + tt) * V_ + n] = v + bias1[n];
                } else {  // MODE 2: pre2
                    if (m < M) {
                        int tt = m >> 4, bb = m & 15;
                        int g = n >> 10, d = n & 1023;
                        C[(((size_t)tt * 512 + (d >> 1)) * 16 + bb) * 8 + g * 2 +
                          (d & 1)] = v + bias1[n] + bias2[n];
                    }
                }
            }
        }
    }
}

// ---------------- persistent encoder ----------------

__global__ __launch_bounds__(256, 2) void enc_persist(
    const float* __restrict__ pre, const float* __restrict__ Whh,
    const float* __restrict__ h0zero, float* __restrict__ c,
    float* __restrict__ enc_out, int* bar) {
    __shared__ float4 red4[4 * 64 * 17];
    __shared__ float zred[256];
    const int bk = blockIdx.x;
    const int tid = threadIdx.x;
    const int wv = tid >> 6, lane = tid & 63;
    const int k0 = wv * 256 + lane * 4;

    float4 wr[2][4];
#pragma unroll
    for (int dd = 0; dd < 2; ++dd) {
        int d = (bk << 1) + dd;
#pragma unroll
        for (int g = 0; g < 4; ++g)
            wr[dd][g] = *(const float4*)(Whh + (size_t)(g * 1024 + d) * H_ + k0);
    }

    int ep = 0;
    for (int t = 0; t < 128; ++t) {
        const float* xsrc;
        size_t xstr;
        if (t == 0) { xsrc = h0zero; xstr = H_; }
        else { xsrc = enc_out + (size_t)(t - 1) * H_; xstr = (size_t)128 * H_; }

        // coalesced pre2 prefetch: [b][g][dd] chunk for this (t, bk)
        float prz[8];
        if (tid < 16) {
            const float* pb = pre + ((size_t)t * 512 + bk) * 128 + tid * 8;
#pragma unroll
            for (int q = 0; q < 8; ++q) prz[q] = pb[q];
        }

        float hloc0 = 0.f, hloc1 = 0.f;
        for (int dd = 0; dd < 2; ++dd) {
            float4 part[16];
#pragma unroll
            for (int b = 0; b < 16; ++b) {
                float4 hv = *(const float4*)(xsrc + (size_t)b * xstr + k0);
                part[b].x = dot4(wr[dd][0], hv);
                part[b].y = dot4(wr[dd][1], hv);
                part[b].z = dot4(wr[dd][2], hv);
                part[b].w = dot4(wr[dd][3], hv);
            }
#pragma unroll
            for (int b = 0; b < 16; ++b) red4[(wv * 64 + lane) * 17 + b] = part[b];
            __syncthreads();
            {
                int v = tid & 63, wq = tid >> 6;
                const float* rf = (const float*)red4;
                float s = 0.f;
#pragma unroll 8
                for (int l = 0; l < 64; ++l) s += rf[(wq * 64 + l) * 68 + v];
                zred[wq * 64 + v] = s;
            }
            __syncthreads();
            if (tid < 16) {
                int b = tid;
                const int d = (bk << 1) + dd;
                float zz[4];
#pragma unroll
                for (int g = 0; g < 4; ++g) {
                    float s = zred[b * 4 + g] + zred[64 + b * 4 + g] +
                              zred[128 + b * 4 + g] + zred[192 + b * 4 + g];
                    zz[g] = s + prz[g * 2 + dd];
                }
                float co = c[b * H_ + d];
                float c2 = sigm(zz[1]) * co + sigm(zz[0]) * tanhf(zz[2]);
                float h2 = sigm(zz[3]) * tanhf(c2);
                c[b * H_ + d] = c2;
                if (dd == 0) hloc0 = h2; else hloc1 = h2;
            }
            __syncthreads();
        }
        if (tid < 16)
            pub2(&enc_out[((size_t)tid * 128 + t) * H_ + (bk << 1)], hloc0, hloc1);
        ++ep;
        gbar(bar, ep, bk);
    }
}

// ---------------- persistent decoder: 3 phases/step ----------------

__global__ __launch_bounds__(256, 2) void dec_persist(
    const float* __restrict__ pre, const float* __restrict__ Whh,
    const float* __restrict__ WihFull, const float* __restrict__ attn_W,
    const float* __restrict__ attn_b, const float* __restrict__ enc_out,
    float* __restrict__ h_ring, float* __restrict__ a_ring,
    float* __restrict__ ct_ring, const float* __restrict__ a0zero,
    float* __restrict__ c, const int* __restrict__ mask2,
    u16* __restrict__ a2bf, int* bar) {
    __shared__ float4 red4[4 * 64 * 17];
    __shared__ float zred[256];
    __shared__ float hq[1024];
    __shared__ float ps[128];
    __shared__ float red[2];
    const int bk = blockIdx.x;
    const int tid = threadIdx.x;
    const int wv = tid >> 6, lane = tid & 63;
    const int kq = (wv & 1) * 512 + lane * 8;
    const bool isA = wv >= 2;
    const bool isH = wv >= 2;

    float4 wr[2][4][2];
#pragma unroll
    for (int dd = 0; dd < 2; ++dd) {
        int d = (bk << 1) + dd;
#pragma unroll
        for (int g = 0; g < 4; ++g) {
            int j = g * 1024 + d;
            const float* wsrc = isA ? (WihFull + (size_t)j * 1536 + 512 + kq)
                                    : (Whh + (size_t)j * H_ + kq);
            wr[dd][g][0] = *(const float4*)(wsrc);
            wr[dd][g][1] = *(const float4*)(wsrc + 4);
        }
    }
    float4 wa2[2][2];
#pragma unroll
    for (int dd = 0; dd < 2; ++dd) {
        int d = (bk << 1) + dd;
        const float* wsrc = attn_W + (size_t)d * 2048 + (isH ? 1024 : 0) + kq;
        wa2[dd][0] = *(const float4*)(wsrc);
        wa2[dd][1] = *(const float4*)(wsrc + 4);
    }

    int ep = 0;
    for (int t = 0; t < T1_; ++t) {
        const float* hsrc;
        size_t hstr;
        if (t == 0) { hsrc = enc_out + (size_t)127 * H_; hstr = (size_t)128 * H_; }
        else { hsrc = h_ring + (size_t)(t - 1) * B_ * H_; hstr = H_; }
        const float* asrc = (t == 0) ? a0zero : (a_ring + (size_t)(t - 1) * B_ * H_);
        float* hcur = h_ring + (size_t)t * B_ * H_;
        float* ctcur = ct_ring + (size_t)t * B_ * H_;
        float* acur = a_ring + (size_t)t * B_ * H_;

        // coalesced pre2 prefetch
        float prz[8];
        if (tid < 16) {
            const float* pb = pre + ((size_t)t * 512 + bk) * 128 + tid * 8;
#pragma unroll
            for (int q = 0; q < 8; ++q) prz[q] = pb[q];
        }

        // ---- phase 1: LSTM for my 2 d ----
        const float* xsrc1 = isA ? asrc : hsrc;
        const size_t xstr1 = isA ? (size_t)H_ : hstr;
        float hloc0 = 0.f, hloc1 = 0.f;
        for (int dd = 0; dd < 2; ++dd) {
            float4 part[16];
#pragma unroll
            for (int b = 0; b < 16; ++b) {
                float4 x0 = *(const float4*)(xsrc1 + (size_t)b * xstr1 + kq);
                float4 x1 = *(const float4*)(xsrc1 + (size_t)b * xstr1 + kq + 4);
                part[b].x = dot4(wr[dd][0][0], x0) + dot4(wr[dd][0][1], x1);
                part[b].y = dot4(wr[dd][1][0], x0) + dot4(wr[dd][1][1], x1);
                part[b].z = dot4(wr[dd][2][0], x0) + dot4(wr[dd][2][1], x1);
                part[b].w = dot4(wr[dd][3][0], x0) + dot4(wr[dd][3][1], x1);
            }
#pragma unroll
            for (int b = 0; b < 16; ++b) red4[(wv * 64 + lane) * 17 + b] = part[b];
            __syncthreads();
            {
                int v = tid & 63, wq = tid >> 6;
                const float* rf = (const float*)red4;
                float s = 0.f;
#pragma unroll 8
                for (int l = 0; l < 64; ++l) s += rf[(wq * 64 + l) * 68 + v];
                zred[wq * 64 + v] = s;
            }
            __syncthreads();
            if (tid < 16) {
                int b = tid;
                const int d = (bk << 1) + dd;
                float zz[4];
#pragma unroll
                for (int g = 0; g < 4; ++g) {
                    float s = zred[b * 4 + g] + zred[64 + b * 4 + g] +
                              zred[128 + b * 4 + g] + zred[192 + b * 4 + g];
                    zz[g] = s + prz[g * 2 + dd];
                }
                float co = c[b * H_ + d];
                float c2 = sigm(zz[1]) * co + sigm(zz[0]) * tanhf(zz[2]);
                float h2 = sigm(zz[3]) * tanhf(c2);
                c[b * H_ + d] = c2;
                if (dd == 0) hloc0 = h2; else hloc1 = h2;
            }
            __syncthreads();
        }
        if (tid < 16) pub2(&hcur[tid * H_ + (bk << 1)], hloc0, hloc1);
        ++ep;
        gbar(bar, ep, bk);

        // ---- phase 2: attention (blocks 0..15) ----
        if (bk < 16) {
            int b = bk;
            *(float4*)(hq + tid * 4) = *(const float4*)(hcur + b * H_ + tid * 4);
            __syncthreads();
            int s = tid >> 1, hf = tid & 1;
            const float* er = enc_out + ((size_t)b * 128 + s) * H_ + hf * 512;
            const float* hr = hq + hf * 512;
            float sc = 0.f;
            for (int k = 0; k < 512; k += 4) {
                float4 e = *(const float4*)(er + k);
                sc += e.x * hr[k] + e.y * hr[k + 1] + e.z * hr[k + 2] + e.w * hr[k + 3];
            }
            sc += __shfl_xor(sc, 1);
            if (hf == 0) ps[s] = (mask2[b * 128 + s] == 1) ? NEGBIG : sc;
            __syncthreads();
            if (tid < 64) {
                float m2 = fmaxf(ps[tid], ps[tid + 64]);
                for (int off = 32; off; off >>= 1) m2 = fmaxf(m2, __shfl_xor(m2, off));
                if (tid == 0) red[0] = m2;
            }
            __syncthreads();
            if (tid < 128) ps[tid] = expf(ps[tid] - red[0]);
            __syncthreads();
            if (tid < 64) {
                float s2 = ps[tid] + ps[tid + 64];
                for (int off = 32; off; off >>= 1) s2 += __shfl_xor(s2, off);
                if (tid == 0) red[1] = 1.f / s2;
            }
            __syncthreads();
            float inv = red[1];
            int d0 = tid * 4;
            float4 av = {0.f, 0.f, 0.f, 0.f};
            for (int s2 = 0; s2 < 128; ++s2) {
                float p = ps[s2] * inv;
                float4 e = *(const float4*)(enc_out + ((size_t)b * 128 + s2) * H_ + d0);
                av.x += p * e.x; av.y += p * e.y; av.z += p * e.z; av.w += p * e.w;
            }
            pub2(&ctcur[b * H_ + d0 + 0], av.x, av.y);
            pub2(&ctcur[b * H_ + d0 + 2], av.z, av.w);
        }
        ++ep;
        gbar(bar, ep, bk);

        // ---- phase 3: a2 for my 2 d ----
        const float* xsrc3 = isH ? hcur : ctcur;
        float aloc0 = 0.f, aloc1 = 0.f;
        for (int dd = 0; dd < 2; ++dd) {
            const int d = (bk << 1) + dd;
            float partA[16];
#pragma unroll
            for (int b = 0; b < 16; ++b) {
                float4 x0 = *(const float4*)(xsrc3 + b * H_ + kq);
                float4 x1 = *(const float4*)(xsrc3 + b * H_ + kq + 4);
                partA[b] = dot4(wa2[dd][0], x0) + dot4(wa2[dd][1], x1);
            }
#pragma unroll
            for (int q = 0; q < 4; ++q)
                red4[(wv * 64 + lane) * 17 + q] =
                    make_float4(partA[q * 4], partA[q * 4 + 1], partA[q * 4 + 2], partA[q * 4 + 3]);
            __syncthreads();
            if (tid < 64) {
                int v = tid & 15, wq = tid >> 4;
                const float* rf = (const float*)red4;
                float s = 0.f;
#pragma unroll 8
                for (int l = 0; l < 64; ++l) s += rf[(wq * 64 + l) * 68 + v];
                zred[wq * 16 + v] = s;
            }
            __syncthreads();
            if (tid < 16) {
                int b = tid;
                float v = zred[b] + zred[16 + b] + zred[32 + b] + zred[48 + b] + attn_b[d];
                v = tanhf(v);
                if (dd == 0) aloc0 = v; else aloc1 = v;
            }
            __syncthreads();
        }
        if (tid < 16) {
            pub2(&acur[tid * H_ + (bk << 1)], aloc0, aloc1);
            unsigned pk2 = (unsigned)f2bf(aloc0) | ((unsigned)f2bf(aloc1) << 16);
            *(unsigned*)&a2bf[((size_t)(t * 16 + tid)) * H_ + (bk << 1)] = pk2;
        }
        ++ep;
        gbar(bar, ep, bk);
    }
}

// ---------------- orchestration ----------------

extern "C" void kernel_launch(void* const* d_in, const int* in_sizes, int n_in,
                              void* d_out, int out_size, void* d_ws, size_t ws_size,
                              hipStream_t stream) {
    const int* in_tok = (const int*)d_in[0];
    const int* out_tok = (const int*)d_in[1];
    const int* mask = (const int*)d_in[2];
    const float* emb_in = (const float*)d_in[3];
    const float* emb_out = (const float*)d_in[4];
    const float* enc_Wih = (const float*)d_in[5];
    const float* enc_Whh = (const float*)d_in[6];
    const float* enc_bih = (const float*)d_in[7];
    const float* enc_bhh = (const float*)d_in[8];
    const float* dec_Wih = (const float*)d_in[9];
    const float* dec_Whh = (const float*)d_in[10];
    const float* dec_bih = (const float*)d_in[11];
    const float* dec_bhh = (const float*)d_in[12];
    const float* attn_W = (const float*)d_in[13];
    const float* attn_b = (const float*)d_in[14];
    const float* out_W = (const float*)d_in[15];
    const float* out_b = (const float*)d_in[16];
    float* out = (float*)d_out;

    char* p = (char*)d_ws;
    auto alloc = [&](size_t bytes) {
        char* r = p;
        p += (bytes + 255) & ~(size_t)255;
        return r;
    };
    u16* A_enc3 = (u16*)alloc((size_t)2048 * 1536 * 2);
    u16* A_dec3 = (u16*)alloc((size_t)2048 * 1536 * 2);
    u16* W_e3 = (u16*)alloc((size_t)4096 * 1536 * 2);
    u16* W_d3 = (u16*)alloc((size_t)4096 * 1536 * 2);
    u16* Wo = (u16*)alloc((size_t)32000 * 1024 * 2);
    float* enc_pre = (float*)alloc((size_t)2048 * 4096 * 4);
    float* dec_pre = (float*)alloc((size_t)2048 * 4096 * 4);
    float* enc_out = (float*)alloc((size_t)16 * 128 * 1024 * 4);
    u16* a2bf = (u16*)alloc((size_t)2048 * 1024 * 2);
    float* h0 = (float*)alloc(16 * 1024 * 4);
    float* c = (float*)alloc(16 * 1024 * 4);
    float* a0 = (float*)alloc(16 * 1024 * 4);
    int* barE = (int*)alloc(4096 * 4);
    int* barD = (int*)alloc(4096 * 4);
    int* mask2 = (int*)alloc(16 * 128 * 4);

    float* h_ring = (float*)A_enc3;
    float* a_ring = h_ring + (size_t)128 * B_ * H_;
    float* ct_ring = a_ring + (size_t)128 * B_ * H_;

    init_k<<<48, 256, 0, stream>>>(h0, barE, mask, mask2);

    split3_rows_k<<<4096, 128, 0, stream>>>(enc_Wih, 512, W_e3, 4096, 1024, 512);
    split3_rows_k<<<4096, 128, 0, stream>>>(dec_Wih, 1536, W_d3, 4096, 1024, 512);
    f32_to_bf16_k<<<32000, 256, 0, stream>>>(out_W, Wo, 32000 * 1024 / 4);
    gather_split_k<<<2048, 128, 0, stream>>>(in_tok, emb_in, A_enc3, 2048);
    gather_split_k<<<2032, 128, 0, stream>>>(out_tok, emb_out, A_dec3, 2032);

    gemm_bt<2><<<dim3(16, 32), 256, 0, stream>>>(A_enc3, W_e3, enc_pre, enc_bih, enc_bhh,
                                                 2048, 4096, 1536);
    gemm_bt<2><<<dim3(16, 32), 256, 0, stream>>>(A_dec3, W_d3, dec_pre, dec_bih, dec_bhh,
                                                 2048, 4096, 1536);

    enc_persist<<<512, 256, 0, stream>>>(enc_pre, enc_Whh, h0, c, enc_out, barE);

    dec_persist<<<512, 256, 0, stream>>>(dec_pre, dec_Whh, dec_Wih, attn_W, attn_b,
                                         enc_out, h_ring, a_ring, ct_ring, a0, c,
                                         mask2, a2bf, barD);

    gemm_bt<1><<<dim3(16, 250), 256, 0, stream>>>(a2bf, Wo, out, out_b, nullptr,
                                                  2048, 32000, 1024);
}

// Round 9
// 8122.610 us; speedup vs baseline: 1.6726x; 1.0272x over previous
//
#include <hip/hip_runtime.h>
#include <hip/hip_bf16.h>
#include <stdint.h>

typedef unsigned short u16;
typedef unsigned long long u64;
typedef __bf16 bf16x8v __attribute__((ext_vector_type(8)));
typedef float f32x4 __attribute__((ext_vector_type(4)));

#define B_ 16
#define S_ 128
#define T1_ 127
#define E_ 512
#define H_ 1024
#define H4_ 4096
#define V_ 32000
#define NEGBIG -1e10f
#define NBLK 512

__device__ __forceinline__ u16 f2bf(float f) {
    union { float f; unsigned u; } v; v.f = f;
    unsigned u = v.u;
    unsigned r = (u + 0x7fffu + ((u >> 16) & 1u)) >> 16;
    return (u16)r;
}
__device__ __forceinline__ float bf2f(u16 h) {
    union { unsigned u; float f; } v; v.u = ((unsigned)h) << 16;
    return v.f;
}
__device__ __forceinline__ float sigm(float x) { return 1.f / (1.f + expf(-x)); }
__device__ __forceinline__ float dot4(float4 a, float4 b) {
    return a.x * b.x + a.y * b.y + a.z * b.z + a.w * b.w;
}
__device__ __forceinline__ void pub2(float* p, float v0, float v1) {
    union { float f[2]; u64 u; } pk;
    pk.f[0] = v0; pk.f[1] = v1;
    atomicExch((u64*)p, pk.u);
}

// ---- grid barrier v5: tournament arrival + SYSTEM-scope load polls ----
// Arrival: 3-level RMW tree (8/line). Release: winner atomicExch 8 rel lines
// (coherence point). Poll: relaxed SYSTEM-scope load = global_load sc0 sc1 —
// bypasses the local (stale, non-coherent) L2, no RMW serialization, no
// buffer_inv fence. This is the coherent-and-fast poll the prior rounds missed.
// bar layout (ints): c1[64] at 0 (stride 16), c2[8] at 1024, c3 at 1152,
// rel[8] at 1216.
__device__ __forceinline__ void gbar(int* bar, int ep, int bk) {
    asm volatile("s_waitcnt vmcnt(0) lgkmcnt(0)" ::: "memory");
    __syncthreads();
    if (threadIdx.x == 0) {
        const int g1 = bk & 63, g2 = g1 >> 3;
        int old = atomicAdd(&bar[g1 * 16], 1);
        if (old == ep * 8 - 1) {
            int old2 = atomicAdd(&bar[1024 + g2 * 16], 1);
            if (old2 == ep * 8 - 1) {
                int old3 = atomicAdd(&bar[1152], 1);
                if (old3 == ep * 8 - 1) {
#pragma unroll
                    for (int j = 0; j < 8; ++j) atomicExch(&bar[1216 + j * 16], ep);
                }
            }
        }
        while (__hip_atomic_load(&bar[1216 + (bk & 7) * 16], __ATOMIC_RELAXED,
                                 __HIP_MEMORY_SCOPE_SYSTEM) < ep)
            __builtin_amdgcn_s_sleep(2);
    }
    __syncthreads();
}

// ---------------- converts / gathers (verified) ----------------

__global__ __launch_bounds__(256) void f32_to_bf16_k(const float* __restrict__ src,
                                                     u16* __restrict__ dst, int n4) {
    int idx = blockIdx.x * 256 + threadIdx.x;
    if (idx >= n4) return;
    float4 v = ((const float4*)src)[idx];
    unsigned lo = (unsigned)f2bf(v.x) | ((unsigned)f2bf(v.y) << 16);
    unsigned hi = (unsigned)f2bf(v.z) | ((unsigned)f2bf(v.w) << 16);
    uint2 pk; pk.x = lo; pk.y = hi;
    *(uint2*)(dst + (size_t)idx * 4) = pk;
}

__global__ __launch_bounds__(128) void split3_rows_k(const float* __restrict__ src,
                                                     int srcStride,
                                                     u16* __restrict__ dst, int nrows,
                                                     int offH2, int offLo) {
    int j = blockIdx.x;
    if (j >= nrows) return;
    int tid = threadIdx.x;
    float4 v = *(const float4*)(src + (size_t)j * srcStride + tid * 4);
    u16 h0 = f2bf(v.x), h1 = f2bf(v.y), h2 = f2bf(v.z), h3 = f2bf(v.w);
    u16 l0 = f2bf(v.x - bf2f(h0)), l1 = f2bf(v.y - bf2f(h1));
    u16 l2 = f2bf(v.z - bf2f(h2)), l3 = f2bf(v.w - bf2f(h3));
    uint2 ph; ph.x = (unsigned)h0 | ((unsigned)h1 << 16); ph.y = (unsigned)h2 | ((unsigned)h3 << 16);
    uint2 pl; pl.x = (unsigned)l0 | ((unsigned)l1 << 16); pl.y = (unsigned)l2 | ((unsigned)l3 << 16);
    u16* base = dst + (size_t)j * 1536 + tid * 4;
    *(uint2*)(base) = ph;
    *(uint2*)(base + offH2) = ph;
    *(uint2*)(base + offLo) = pl;
}

__global__ __launch_bounds__(128) void gather_split_k(const int* __restrict__ toks,
                                                      const float* __restrict__ emb,
                                                      u16* __restrict__ A, int nrows) {
    int m = blockIdx.x;
    if (m >= nrows) return;
    int tIdx = m >> 4, b = m & 15;
    int tok = toks[b * 128 + tIdx];
    int tid = threadIdx.x;
    float4 v = *(const float4*)(emb + (size_t)tok * E_ + tid * 4);
    u16 h0 = f2bf(v.x), h1 = f2bf(v.y), h2 = f2bf(v.z), h3 = f2bf(v.w);
    u16 l0 = f2bf(v.x - bf2f(h0)), l1 = f2bf(v.y - bf2f(h1));
    u16 l2 = f2bf(v.z - bf2f(h2)), l3 = f2bf(v.w - bf2f(h3));
    uint2 ph; ph.x = (unsigned)h0 | ((unsigned)h1 << 16); ph.y = (unsigned)h2 | ((unsigned)h3 << 16);
    uint2 pl; pl.x = (unsigned)l0 | ((unsigned)l1 << 16); pl.y = (unsigned)l2 | ((unsigned)l3 << 16);
    u16* base = A + (size_t)m * 1536 + tid * 4;
    *(uint2*)(base) = ph;
    *(uint2*)(base + 512) = ph;
    *(uint2*)(base + 1024) = pl;
}

// zero state (h0|c|a0 = 48K floats) + barrier arrays (8192 ints) + mask2
__global__ __launch_bounds__(256) void init_k(float* __restrict__ zero1,
                                              int* __restrict__ zero2,
                                              const int* __restrict__ mask,
                                              int* __restrict__ mask2) {
    int idx = blockIdx.x * 256 + threadIdx.x;
    float4 z = {0.f, 0.f, 0.f, 0.f};
    if (idx < 12288) ((float4*)zero1)[idx] = z;
    if (idx < 2048) { int4 zi = {0, 0, 0, 0}; ((int4*)zero2)[idx] = zi; }
    if (blockIdx.x == 0 && threadIdx.x < 16) {
        int b = threadIdx.x;
        int first0 = 128;
        for (int s = 0; s < 128; ++s) {
            if (mask[b * 128 + s] == 0) { first0 = s; break; }
        }
        if (first0 == 128) first0 = 0;
        int len = first0 - 1;
        int ix = (len < 0) ? 127 : len;
        for (int s = 0; s < 128; ++s) mask2[b * 128 + s] = mask[b * 128 + s];
        mask2[b * 128 + ix] = 0;
    }
}

// ---------------- bf16 MFMA GEMM (verified) ----------------
// MODE 1: logits. MODE 2: pre2 layout [t][d>>1][b][g][d&1].

#define GLD_LDS(g, l) \
    __builtin_amdgcn_global_load_lds((const __attribute__((address_space(1))) void*)(g), \
                                     (__attribute__((address_space(3))) void*)(l), 16, 0, 0)

template <int MODE>
__global__ __launch_bounds__(256) void gemm_bt(const u16* __restrict__ A,
                                               const u16* __restrict__ Bt,
                                               float* __restrict__ C,
                                               const float* __restrict__ bias1,
                                               const float* __restrict__ bias2,
                                               int M, int N, int K) {
    __shared__ u16 As[128 * 32];
    __shared__ u16 Bs[128 * 32];
    const int tid = threadIdx.x;
    const int bm = blockIdx.x, bn = blockIdx.y;
    const int lane = tid & 63, w = tid >> 6;
    const int wm = (w >> 1) * 64, wn = (w & 1) * 64;
    f32x4 acc[4][4] = {};

    const int r0 = tid >> 2;
    const int c0 = (tid & 3) * 8;
    const u16* ga0 = A + (size_t)(bm * 128 + r0) * K + c0;
    const u16* ga1 = A + (size_t)(bm * 128 + 64 + r0) * K + c0;
    const u16* gb0 = Bt + (size_t)(bn * 128 + r0) * K + c0;
    const u16* gb1 = Bt + (size_t)(bn * 128 + 64 + r0) * K + c0;
    u16* lA0 = As + tid * 8;
    u16* lA1 = As + 2048 + tid * 8;
    u16* lB0 = Bs + tid * 8;
    u16* lB1 = Bs + 2048 + tid * 8;

    const int fl = lane & 15, kg = lane >> 4;

    for (int k0 = 0; k0 < K; k0 += 32) {
        __syncthreads();
        GLD_LDS(ga0 + k0, lA0);
        GLD_LDS(ga1 + k0, lA1);
        GLD_LDS(gb0 + k0, lB0);
        GLD_LDS(gb1 + k0, lB1);
        __syncthreads();
        bf16x8v af[4], bfv[4];
#pragma unroll
        for (int i = 0; i < 4; ++i)
            af[i] = *(const bf16x8v*)(As + (wm + i * 16 + fl) * 32 + kg * 8);
#pragma unroll
        for (int j = 0; j < 4; ++j)
            bfv[j] = *(const bf16x8v*)(Bs + (wn + j * 16 + fl) * 32 + kg * 8);
#pragma unroll
        for (int i = 0; i < 4; ++i)
#pragma unroll
            for (int j = 0; j < 4; ++j)
                acc[i][j] = __builtin_amdgcn_mfma_f32_16x16x32_bf16(af[i], bfv[j], acc[i][j], 0, 0, 0);
    }

    const int coll = lane & 15;
    const int rowb = (lane >> 4) * 4;
#pragma unroll
    for (int i = 0; i < 4; ++i) {
#pragma unroll
        for (int j = 0; j < 4; ++j) {
#pragma unroll
            for (int r = 0; r < 4; ++r) {
                int m = bm * 128 + wm + i * 16 + rowb + r;
                int n = bn * 128 + wn + j * 16 + coll;
                float v = acc[i][j][r];
                if (MODE == 1) {
                    int tt = m >> 4, bb = m & 15;
                    if (tt < T1_) C[((size_t)bb * T1_ + tt) * V_ + n] = v + bias1[n];
                } else {  // MODE 2: pre2
                    if (m < M) {
                        int tt = m >> 4, bb = m & 15;
                        int g = n >> 10, d = n & 1023;
                        C[(((size_t)tt * 512 + (d >> 1)) * 16 + bb) * 8 + g * 2 +
                          (d & 1)] = v + bias1[n] + bias2[n];
                    }
                }
            }
        }
    }
}

// ---------------- persistent encoder ----------------

__global__ __launch_bounds__(256, 2) void enc_persist(
    const float* __restrict__ pre, const float* __restrict__ Whh,
    const float* __restrict__ h0zero, float* __restrict__ c,
    float* __restrict__ enc_out, int* bar) {
    __shared__ float4 red4[4 * 64 * 17];
    __shared__ float zred[256];
    const int bk = blockIdx.x;
    const int tid = threadIdx.x;
    const int wv = tid >> 6, lane = tid & 63;
    const int k0 = wv * 256 + lane * 4;

    float4 wr[2][4];
#pragma unroll
    for (int dd = 0; dd < 2; ++dd) {
        int d = (bk << 1) + dd;
#pragma unroll
        for (int g = 0; g < 4; ++g)
            wr[dd][g] = *(const float4*)(Whh + (size_t)(g * 1024 + d) * H_ + k0);
    }

    int ep = 0;
    for (int t = 0; t < 128; ++t) {
        const float* xsrc;
        size_t xstr;
        if (t == 0) { xsrc = h0zero; xstr = H_; }
        else { xsrc = enc_out + (size_t)(t - 1) * H_; xstr = (size_t)128 * H_; }

        // coalesced pre2 prefetch: [b][g][dd] chunk for this (t, bk)
        float prz[8];
        if (tid < 16) {
            const float* pb = pre + ((size_t)t * 512 + bk) * 128 + tid * 8;
#pragma unroll
            for (int q = 0; q < 8; ++q) prz[q] = pb[q];
        }

        float hloc0 = 0.f, hloc1 = 0.f;
        for (int dd = 0; dd < 2; ++dd) {
            float4 part[16];
#pragma unroll
            for (int b = 0; b < 16; ++b) {
                float4 hv = *(const float4*)(xsrc + (size_t)b * xstr + k0);
                part[b].x = dot4(wr[dd][0], hv);
                part[b].y = dot4(wr[dd][1], hv);
                part[b].z = dot4(wr[dd][2], hv);
                part[b].w = dot4(wr[dd][3], hv);
            }
#pragma unroll
            for (int b = 0; b < 16; ++b) red4[(wv * 64 + lane) * 17 + b] = part[b];
            __syncthreads();
            {
                int v = tid & 63, wq = tid >> 6;
                const float* rf = (const float*)red4;
                float s = 0.f;
#pragma unroll 8
                for (int l = 0; l < 64; ++l) s += rf[(wq * 64 + l) * 68 + v];
                zred[wq * 64 + v] = s;
            }
            __syncthreads();
            if (tid < 16) {
                int b = tid;
                const int d = (bk << 1) + dd;
                float zz[4];
#pragma unroll
                for (int g = 0; g < 4; ++g) {
                    float s = zred[b * 4 + g] + zred[64 + b * 4 + g] +
                              zred[128 + b * 4 + g] + zred[192 + b * 4 + g];
                    zz[g] = s + prz[g * 2 + dd];
                }
                float co = c[b * H_ + d];
                float c2 = sigm(zz[1]) * co + sigm(zz[0]) * tanhf(zz[2]);
                float h2 = sigm(zz[3]) * tanhf(c2);
                c[b * H_ + d] = c2;
                if (dd == 0) hloc0 = h2; else hloc1 = h2;
            }
            __syncthreads();
        }
        if (tid < 16)
            pub2(&enc_out[((size_t)tid * 128 + t) * H_ + (bk << 1)], hloc0, hloc1);
        ++ep;
        gbar(bar, ep, bk);
    }
}

// ---------------- persistent decoder: 3 phases/step ----------------

__global__ __launch_bounds__(256, 2) void dec_persist(
    const float* __restrict__ pre, const float* __restrict__ Whh,
    const float* __restrict__ WihFull, const float* __restrict__ attn_W,
    const float* __restrict__ attn_b, const float* __restrict__ enc_out,
    float* __restrict__ h_ring, float* __restrict__ a_ring,
    float* __restrict__ ct_ring, const float* __restrict__ a0zero,
    float* __restrict__ c, const int* __restrict__ mask2,
    u16* __restrict__ a2bf, int* bar) {
    __shared__ float4 red4[4 * 64 * 17];
    __shared__ float zred[256];
    __shared__ float hq[1024];
    __shared__ float ps[128];
    __shared__ float red[2];
    const int bk = blockIdx.x;
    const int tid = threadIdx.x;
    const int wv = tid >> 6, lane = tid & 63;
    const int kq = (wv & 1) * 512 + lane * 8;
    const bool isA = wv >= 2;
    const bool isH = wv >= 2;

    float4 wr[2][4][2];
#pragma unroll
    for (int dd = 0; dd < 2; ++dd) {
        int d = (bk << 1) + dd;
#pragma unroll
        for (int g = 0; g < 4; ++g) {
            int j = g * 1024 + d;
            const float* wsrc = isA ? (WihFull + (size_t)j * 1536 + 512 + kq)
                                    : (Whh + (size_t)j * H_ + kq);
            wr[dd][g][0] = *(const float4*)(wsrc);
            wr[dd][g][1] = *(const float4*)(wsrc + 4);
        }
    }
    float4 wa2[2][2];
#pragma unroll
    for (int dd = 0; dd < 2; ++dd) {
        int d = (bk << 1) + dd;
        const float* wsrc = attn_W + (size_t)d * 2048 + (isH ? 1024 : 0) + kq;
        wa2[dd][0] = *(const float4*)(wsrc);
        wa2[dd][1] = *(const float4*)(wsrc + 4);
    }

    int ep = 0;
    for (int t = 0; t < T1_; ++t) {
        const float* hsrc;
        size_t hstr;
        if (t == 0) { hsrc = enc_out + (size_t)127 * H_; hstr = (size_t)128 * H_; }
        else { hsrc = h_ring + (size_t)(t - 1) * B_ * H_; hstr = H_; }
        const float* asrc = (t == 0) ? a0zero : (a_ring + (size_t)(t - 1) * B_ * H_);
        float* hcur = h_ring + (size_t)t * B_ * H_;
        float* ctcur = ct_ring + (size_t)t * B_ * H_;
        float* acur = a_ring + (size_t)t * B_ * H_;

        // coalesced pre2 prefetch
        float prz[8];
        if (tid < 16) {
            const float* pb = pre + ((size_t)t * 512 + bk) * 128 + tid * 8;
#pragma unroll
            for (int q = 0; q < 8; ++q) prz[q] = pb[q];
        }

        // ---- phase 1: LSTM for my 2 d ----
        const float* xsrc1 = isA ? asrc : hsrc;
        const size_t xstr1 = isA ? (size_t)H_ : hstr;
        float hloc0 = 0.f, hloc1 = 0.f;
        for (int dd = 0; dd < 2; ++dd) {
            float4 part[16];
#pragma unroll
            for (int b = 0; b < 16; ++b) {
                float4 x0 = *(const float4*)(xsrc1 + (size_t)b * xstr1 + kq);
                float4 x1 = *(const float4*)(xsrc1 + (size_t)b * xstr1 + kq + 4);
                part[b].x = dot4(wr[dd][0][0], x0) + dot4(wr[dd][0][1], x1);
                part[b].y = dot4(wr[dd][1][0], x0) + dot4(wr[dd][1][1], x1);
                part[b].z = dot4(wr[dd][2][0], x0) + dot4(wr[dd][2][1], x1);
                part[b].w = dot4(wr[dd][3][0], x0) + dot4(wr[dd][3][1], x1);
            }
#pragma unroll
            for (int b = 0; b < 16; ++b) red4[(wv * 64 + lane) * 17 + b] = part[b];
            __syncthreads();
            {
                int v = tid & 63, wq = tid >> 6;
                const float* rf = (const float*)red4;
                float s = 0.f;
#pragma unroll 8
                for (int l = 0; l < 64; ++l) s += rf[(wq * 64 + l) * 68 + v];
                zred[wq * 64 + v] = s;
            }
            __syncthreads();
            if (tid < 16) {
                int b = tid;
                const int d = (bk << 1) + dd;
                float zz[4];
#pragma unroll
                for (int g = 0; g < 4; ++g) {
                    float s = zred[b * 4 + g] + zred[64 + b * 4 + g] +
                              zred[128 + b * 4 + g] + zred[192 + b * 4 + g];
                    zz[g] = s + prz[g * 2 + dd];
                }
                float co = c[b * H_ + d];
                float c2 = sigm(zz[1]) * co + sigm(zz[0]) * tanhf(zz[2]);
                float h2 = sigm(zz[3]) * tanhf(c2);
                c[b * H_ + d] = c2;
                if (dd == 0) hloc0 = h2; else hloc1 = h2;
            }
            __syncthreads();
        }
        if (tid < 16) pub2(&hcur[tid * H_ + (bk << 1)], hloc0, hloc1);
        ++ep;
        gbar(bar, ep, bk);

        // ---- phase 2: attention (blocks 0..15) ----
        if (bk < 16) {
            int b = bk;
            *(float4*)(hq + tid * 4) = *(const float4*)(hcur + b * H_ + tid * 4);
            __syncthreads();
            int s = tid >> 1, hf = tid & 1;
            const float* er = enc_out + ((size_t)b * 128 + s) * H_ + hf * 512;
            const float* hr = hq + hf * 512;
            float sc = 0.f;
            for (int k = 0; k < 512; k += 4) {
                float4 e = *(const float4*)(er + k);
                sc += e.x * hr[k] + e.y * hr[k + 1] + e.z * hr[k + 2] + e.w * hr[k + 3];
            }
            sc += __shfl_xor(sc, 1);
            if (hf == 0) ps[s] = (mask2[b * 128 + s] == 1) ? NEGBIG : sc;
            __syncthreads();
            if (tid < 64) {
                float m2 = fmaxf(ps[tid], ps[tid + 64]);
                for (int off = 32; off; off >>= 1) m2 = fmaxf(m2, __shfl_xor(m2, off));
                if (tid == 0) red[0] = m2;
            }
            __syncthreads();
            if (tid < 128) ps[tid] = expf(ps[tid] - red[0]);
            __syncthreads();
            if (tid < 64) {
                float s2 = ps[tid] + ps[tid + 64];
                for (int off = 32; off; off >>= 1) s2 += __shfl_xor(s2, off);
                if (tid == 0) red[1] = 1.f / s2;
            }
            __syncthreads();
            float inv = red[1];
            int d0 = tid * 4;
            float4 av = {0.f, 0.f, 0.f, 0.f};
            for (int s2 = 0; s2 < 128; ++s2) {
                float p = ps[s2] * inv;
                float4 e = *(const float4*)(enc_out + ((size_t)b * 128 + s2) * H_ + d0);
                av.x += p * e.x; av.y += p * e.y; av.z += p * e.z; av.w += p * e.w;
            }
            pub2(&ctcur[b * H_ + d0 + 0], av.x, av.y);
            pub2(&ctcur[b * H_ + d0 + 2], av.z, av.w);
        }
        ++ep;
        gbar(bar, ep, bk);

        // ---- phase 3: a2 for my 2 d ----
        const float* xsrc3 = isH ? hcur : ctcur;
        float aloc0 = 0.f, aloc1 = 0.f;
        for (int dd = 0; dd < 2; ++dd) {
            const int d = (bk << 1) + dd;
            float partA[16];
#pragma unroll
            for (int b = 0; b < 16; ++b) {
                float4 x0 = *(const float4*)(xsrc3 + b * H_ + kq);
                float4 x1 = *(const float4*)(xsrc3 + b * H_ + kq + 4);
                partA[b] = dot4(wa2[dd][0], x0) + dot4(wa2[dd][1], x1);
            }
#pragma unroll
            for (int q = 0; q < 4; ++q)
                red4[(wv * 64 + lane) * 17 + q] =
                    make_float4(partA[q * 4], partA[q * 4 + 1], partA[q * 4 + 2], partA[q * 4 + 3]);
            __syncthreads();
            if (tid < 64) {
                int v = tid & 15, wq = tid >> 4;
                const float* rf = (const float*)red4;
                float s = 0.f;
#pragma unroll 8
                for (int l = 0; l < 64; ++l) s += rf[(wq * 64 + l) * 68 + v];
                zred[wq * 16 + v] = s;
            }
            __syncthreads();
            if (tid < 16) {
                int b = tid;
                float v = zred[b] + zred[16 + b] + zred[32 + b] + zred[48 + b] + attn_b[d];
                v = tanhf(v);
                if (dd == 0) aloc0 = v; else aloc1 = v;
            }
            __syncthreads();
        }
        if (tid < 16) {
            pub2(&acur[tid * H_ + (bk << 1)], aloc0, aloc1);
            unsigned pk2 = (unsigned)f2bf(aloc0) | ((unsigned)f2bf(aloc1) << 16);
            *(unsigned*)&a2bf[((size_t)(t * 16 + tid)) * H_ + (bk << 1)] = pk2;
        }
        ++ep;
        gbar(bar, ep, bk);
    }
}

// ---------------- orchestration ----------------

extern "C" void kernel_launch(void* const* d_in, const int* in_sizes, int n_in,
                              void* d_out, int out_size, void* d_ws, size_t ws_size,
                              hipStream_t stream) {
    const int* in_tok = (const int*)d_in[0];
    const int* out_tok = (const int*)d_in[1];
    const int* mask = (const int*)d_in[2];
    const float* emb_in = (const float*)d_in[3];
    const float* emb_out = (const float*)d_in[4];
    const float* enc_Wih = (const float*)d_in[5];
    const float* enc_Whh = (const float*)d_in[6];
    const float* enc_bih = (const float*)d_in[7];
    const float* enc_bhh = (const float*)d_in[8];
    const float* dec_Wih = (const float*)d_in[9];
    const float* dec_Whh = (const float*)d_in[10];
    const float* dec_bih = (const float*)d_in[11];
    const float* dec_bhh = (const float*)d_in[12];
    const float* attn_W = (const float*)d_in[13];
    const float* attn_b = (const float*)d_in[14];
    const float* out_W = (const float*)d_in[15];
    const float* out_b = (const float*)d_in[16];
    float* out = (float*)d_out;

    char* p = (char*)d_ws;
    auto alloc = [&](size_t bytes) {
        char* r = p;
        p += (bytes + 255) & ~(size_t)255;
        return r;
    };
    u16* A_enc3 = (u16*)alloc((size_t)2048 * 1536 * 2);
    u16* A_dec3 = (u16*)alloc((size_t)2048 * 1536 * 2);
    u16* W_e3 = (u16*)alloc((size_t)4096 * 1536 * 2);
    u16* W_d3 = (u16*)alloc((size_t)4096 * 1536 * 2);
    u16* Wo = (u16*)alloc((size_t)32000 * 1024 * 2);
    float* enc_pre = (float*)alloc((size_t)2048 * 4096 * 4);
    float* dec_pre = (float*)alloc((size_t)2048 * 4096 * 4);
    float* enc_out = (float*)alloc((size_t)16 * 128 * 1024 * 4);
    u16* a2bf = (u16*)alloc((size_t)2048 * 1024 * 2);
    float* h0 = (float*)alloc(16 * 1024 * 4);
    float* c = (float*)alloc(16 * 1024 * 4);
    float* a0 = (float*)alloc(16 * 1024 * 4);
    int* barE = (int*)alloc(4096 * 4);
    int* barD = (int*)alloc(4096 * 4);
    int* mask2 = (int*)alloc(16 * 128 * 4);

    float* h_ring = (float*)A_enc3;
    float* a_ring = h_ring + (size_t)128 * B_ * H_;
    float* ct_ring = a_ring + (size_t)128 * B_ * H_;

    init_k<<<48, 256, 0, stream>>>(h0, barE, mask, mask2);

    split3_rows_k<<<4096, 128, 0, stream>>>(enc_Wih, 512, W_e3, 4096, 1024, 512);
    split3_rows_k<<<4096, 128, 0, stream>>>(dec_Wih, 1536, W_d3, 4096, 1024, 512);
    f32_to_bf16_k<<<32000, 256, 0, stream>>>(out_W, Wo, 32000 * 1024 / 4);
    gather_split_k<<<2048, 128, 0, stream>>>(in_tok, emb_in, A_enc3, 2048);
    gather_split_k<<<2032, 128, 0, stream>>>(out_tok, emb_out, A_dec3, 2032);

    gemm_bt<2><<<dim3(16, 32), 256, 0, stream>>>(A_enc3, W_e3, enc_pre, enc_bih, enc_bhh,
                                                 2048, 4096, 1536);
    gemm_bt<2><<<dim3(16, 32), 256, 0, stream>>>(A_dec3, W_d3, dec_pre, dec_bih, dec_bhh,
                                                 2048, 4096, 1536);

    enc_persist<<<512, 256, 0, stream>>>(enc_pre, enc_Whh, h0, c, enc_out, barE);

    dec_persist<<<512, 256, 0, stream>>>(dec_pre, dec_Whh, dec_Wih, attn_W, attn_b,
                                         enc_out, h_ring, a_ring, ct_ring, a0, c,
                                         mask2, a2bf, barD);

    gemm_bt<1><<<dim3(16, 250), 256, 0, stream>>>(a2bf, Wo, out, out_b, nullptr,
                                                  2048, 32000, 1024);
}

// Round 10
// 4640.285 us; speedup vs baseline: 2.9278x; 1.7505x over previous
//
#include <hip/hip_runtime.h>
#include <hip/hip_bf16.h>
#include <stdint.h>

typedef unsigned short u16;
typedef unsigned long long u64;
typedef __bf16 bf16x8v __attribute__((ext_vector_type(8)));
typedef float f32x4 __attribute__((ext_vector_type(4)));

#define B_ 16
#define S_ 128
#define T1_ 127
#define E_ 512
#define H_ 1024
#define H4_ 4096
#define V_ 32000
#define NEGBIG -1e10f
#define NBLK 512

__device__ __forceinline__ u16 f2bf(float f) {
    union { float f; unsigned u; } v; v.f = f;
    unsigned u = v.u;
    unsigned r = (u + 0x7fffu + ((u >> 16) & 1u)) >> 16;
    return (u16)r;
}
__device__ __forceinline__ float bf2f(u16 h) {
    union { unsigned u; float f; } v; v.u = ((unsigned)h) << 16;
    return v.f;
}
__device__ __forceinline__ float sigm(float x) { return 1.f / (1.f + expf(-x)); }
__device__ __forceinline__ float dot4(float4 a, float4 b) {
    return a.x * b.x + a.y * b.y + a.z * b.z + a.w * b.w;
}
__device__ __forceinline__ void pub2(float* p, float v0, float v1) {
    union { float f[2]; u64 u; } pk;
    pk.f[0] = v0; pk.f[1] = v1;
    atomicExch((u64*)p, pk.u);
}

// ---- grid barrier v5 (proven ~4.5us): tournament RMW arrival + system-scope
// load polls (no fences, no buffer_inv). ----
__device__ __forceinline__ void gbar(int* bar, int ep, int bk) {
    asm volatile("s_waitcnt vmcnt(0) lgkmcnt(0)" ::: "memory");
    __syncthreads();
    if (threadIdx.x == 0) {
        const int g1 = bk & 63, g2 = g1 >> 3;
        int old = atomicAdd(&bar[g1 * 16], 1);
        if (old == ep * 8 - 1) {
            int old2 = atomicAdd(&bar[1024 + g2 * 16], 1);
            if (old2 == ep * 8 - 1) {
                int old3 = atomicAdd(&bar[1152], 1);
                if (old3 == ep * 8 - 1) {
#pragma unroll
                    for (int j = 0; j < 8; ++j) atomicExch(&bar[1216 + j * 16], ep);
                }
            }
        }
        while (__hip_atomic_load(&bar[1216 + (bk & 7) * 16], __ATOMIC_RELAXED,
                                 __HIP_MEMORY_SCOPE_SYSTEM) < ep)
            __builtin_amdgcn_s_sleep(2);
    }
    __syncthreads();
}

// ---------------- converts / gathers ----------------

__global__ __launch_bounds__(256) void f32_to_bf16_k(const float* __restrict__ src,
                                                     u16* __restrict__ dst, int n4) {
    int idx = blockIdx.x * 256 + threadIdx.x;
    if (idx >= n4) return;
    float4 v = ((const float4*)src)[idx];
    unsigned lo = (unsigned)f2bf(v.x) | ((unsigned)f2bf(v.y) << 16);
    unsigned hi = (unsigned)f2bf(v.z) | ((unsigned)f2bf(v.w) << 16);
    uint2 pk; pk.x = lo; pk.y = hi;
    *(uint2*)(dst + (size_t)idx * 4) = pk;
}

// 512-wide row -> 1536-wide split row (128 threads)
__global__ __launch_bounds__(128) void split3_rows_k(const float* __restrict__ src,
                                                     int srcStride,
                                                     u16* __restrict__ dst, int nrows,
                                                     int offH2, int offLo) {
    int j = blockIdx.x;
    if (j >= nrows) return;
    int tid = threadIdx.x;
    float4 v = *(const float4*)(src + (size_t)j * srcStride + tid * 4);
    u16 h0 = f2bf(v.x), h1 = f2bf(v.y), h2 = f2bf(v.z), h3 = f2bf(v.w);
    u16 l0 = f2bf(v.x - bf2f(h0)), l1 = f2bf(v.y - bf2f(h1));
    u16 l2 = f2bf(v.z - bf2f(h2)), l3 = f2bf(v.w - bf2f(h3));
    uint2 ph; ph.x = (unsigned)h0 | ((unsigned)h1 << 16); ph.y = (unsigned)h2 | ((unsigned)h3 << 16);
    uint2 pl; pl.x = (unsigned)l0 | ((unsigned)l1 << 16); pl.y = (unsigned)l2 | ((unsigned)l3 << 16);
    u16* base = dst + (size_t)j * 1536 + tid * 4;
    *(uint2*)(base) = ph;
    *(uint2*)(base + offH2) = ph;
    *(uint2*)(base + offLo) = pl;
}

// 1024-wide row -> 3072-wide split row (256 threads)
// A-side (activations): offH2=1024, offLo=2048 -> [hi|hi|lo]
// B-side (weights):     offH2=2048, offLo=1024 -> [hi|lo|hi]
__global__ __launch_bounds__(256) void split3_1024_k(const float* __restrict__ src,
                                                     int srcStride,
                                                     u16* __restrict__ dst,
                                                     int offH2, int offLo) {
    int j = blockIdx.x, tid = threadIdx.x;
    float4 v = *(const float4*)(src + (size_t)j * srcStride + tid * 4);
    u16 h0 = f2bf(v.x), h1 = f2bf(v.y), h2 = f2bf(v.z), h3 = f2bf(v.w);
    u16 l0 = f2bf(v.x - bf2f(h0)), l1 = f2bf(v.y - bf2f(h1));
    u16 l2 = f2bf(v.z - bf2f(h2)), l3 = f2bf(v.w - bf2f(h3));
    uint2 ph; ph.x = (unsigned)h0 | ((unsigned)h1 << 16); ph.y = (unsigned)h2 | ((unsigned)h3 << 16);
    uint2 pl; pl.x = (unsigned)l0 | ((unsigned)l1 << 16); pl.y = (unsigned)l2 | ((unsigned)l3 << 16);
    u16* base = dst + (size_t)j * 3072 + tid * 4;
    *(uint2*)(base) = ph;
    *(uint2*)(base + offH2) = ph;
    *(uint2*)(base + offLo) = pl;
}

__global__ __launch_bounds__(128) void gather_split_k(const int* __restrict__ toks,
                                                      const float* __restrict__ emb,
                                                      u16* __restrict__ A, int nrows) {
    int m = blockIdx.x;
    if (m >= nrows) return;
    int tIdx = m >> 4, b = m & 15;
    int tok = toks[b * 128 + tIdx];
    int tid = threadIdx.x;
    float4 v = *(const float4*)(emb + (size_t)tok * E_ + tid * 4);
    u16 h0 = f2bf(v.x), h1 = f2bf(v.y), h2 = f2bf(v.z), h3 = f2bf(v.w);
    u16 l0 = f2bf(v.x - bf2f(h0)), l1 = f2bf(v.y - bf2f(h1));
    u16 l2 = f2bf(v.z - bf2f(h2)), l3 = f2bf(v.w - bf2f(h3));
    uint2 ph; ph.x = (unsigned)h0 | ((unsigned)h1 << 16); ph.y = (unsigned)h2 | ((unsigned)h3 << 16);
    uint2 pl; pl.x = (unsigned)l0 | ((unsigned)l1 << 16); pl.y = (unsigned)l2 | ((unsigned)l3 << 16);
    u16* base = A + (size_t)m * 1536 + tid * 4;
    *(uint2*)(base) = ph;
    *(uint2*)(base + 512) = ph;
    *(uint2*)(base + 1024) = pl;
}

// zero state (h0|c|a0) + barrier arrays + mask2
__global__ __launch_bounds__(256) void init_k(float* __restrict__ zero1,
                                              int* __restrict__ zero2,
                                              const int* __restrict__ mask,
                                              int* __restrict__ mask2) {
    int idx = blockIdx.x * 256 + threadIdx.x;
    float4 z = {0.f, 0.f, 0.f, 0.f};
    if (idx < 12288) ((float4*)zero1)[idx] = z;
    if (idx < 2048) { int4 zi = {0, 0, 0, 0}; ((int4*)zero2)[idx] = zi; }
    if (blockIdx.x == 0 && threadIdx.x < 16) {
        int b = threadIdx.x;
        int first0 = 128;
        for (int s = 0; s < 128; ++s) {
            if (mask[b * 128 + s] == 0) { first0 = s; break; }
        }
        if (first0 == 128) first0 = 0;
        int len = first0 - 1;
        int ix = (len < 0) ? 127 : len;
        for (int s = 0; s < 128; ++s) mask2[b * 128 + s] = mask[b * 128 + s];
        mask2[b * 128 + ix] = 0;
    }
}

// ---------------- bf16 MFMA GEMM ----------------
// MODE 1: logits. MODE 2: pre2 [t][d>>1][b][g][d&1]. MODE 3: PE2 [d>>1][b][s][d&1].

#define GLD_LDS(g, l) \
    __builtin_amdgcn_global_load_lds((const __attribute__((address_space(1))) void*)(g), \
                                     (__attribute__((address_space(3))) void*)(l), 16, 0, 0)

template <int MODE>
__global__ __launch_bounds__(256) void gemm_bt(const u16* __restrict__ A,
                                               const u16* __restrict__ Bt,
                                               float* __restrict__ C,
                                               const float* __restrict__ bias1,
                                               const float* __restrict__ bias2,
                                               int M, int N, int K) {
    __shared__ u16 As[128 * 32];
    __shared__ u16 Bs[128 * 32];
    const int tid = threadIdx.x;
    const int bm = blockIdx.x, bn = blockIdx.y;
    const int lane = tid & 63, w = tid >> 6;
    const int wm = (w >> 1) * 64, wn = (w & 1) * 64;
    f32x4 acc[4][4] = {};

    const int r0 = tid >> 2;
    const int c0 = (tid & 3) * 8;
    const u16* ga0 = A + (size_t)(bm * 128 + r0) * K + c0;
    const u16* ga1 = A + (size_t)(bm * 128 + 64 + r0) * K + c0;
    const u16* gb0 = Bt + (size_t)(bn * 128 + r0) * K + c0;
    const u16* gb1 = Bt + (size_t)(bn * 128 + 64 + r0) * K + c0;
    u16* lA0 = As + tid * 8;
    u16* lA1 = As + 2048 + tid * 8;
    u16* lB0 = Bs + tid * 8;
    u16* lB1 = Bs + 2048 + tid * 8;

    const int fl = lane & 15, kg = lane >> 4;

    for (int k0 = 0; k0 < K; k0 += 32) {
        __syncthreads();
        GLD_LDS(ga0 + k0, lA0);
        GLD_LDS(ga1 + k0, lA1);
        GLD_LDS(gb0 + k0, lB0);
        GLD_LDS(gb1 + k0, lB1);
        __syncthreads();
        bf16x8v af[4], bfv[4];
#pragma unroll
        for (int i = 0; i < 4; ++i)
            af[i] = *(const bf16x8v*)(As + (wm + i * 16 + fl) * 32 + kg * 8);
#pragma unroll
        for (int j = 0; j < 4; ++j)
            bfv[j] = *(const bf16x8v*)(Bs + (wn + j * 16 + fl) * 32 + kg * 8);
#pragma unroll
        for (int i = 0; i < 4; ++i)
#pragma unroll
            for (int j = 0; j < 4; ++j)
                acc[i][j] = __builtin_amdgcn_mfma_f32_16x16x32_bf16(af[i], bfv[j], acc[i][j], 0, 0, 0);
    }

    const int coll = lane & 15;
    const int rowb = (lane >> 4) * 4;
#pragma unroll
    for (int i = 0; i < 4; ++i) {
#pragma unroll
        for (int j = 0; j < 4; ++j) {
#pragma unroll
            for (int r = 0; r < 4; ++r) {
                int m = bm * 128 + wm + i * 16 + rowb + r;
                int n = bn * 128 + wn + j * 16 + coll;
                float v = acc[i][j][r];
                if (MODE == 1) {
                    int tt = m >> 4, bb = m & 15;
                    if (tt < T1_) C[((size_t)bb * T1_ + tt) * V_ + n] = v + bias1[n];
                } else if (MODE == 2) {
                    if (m < M) {
                        int tt = m >> 4, bb = m & 15;
                        int g = n >> 10, d = n & 1023;
                        C[(((size_t)tt * 512 + (d >> 1)) * 16 + bb) * 8 + g * 2 +
                          (d & 1)] = v + bias1[n] + bias2[n];
                    }
                } else {  // MODE 3: PE2[d>>1][b][s][d&1]; m = b*128+s
                    int b = m >> 7, s = m & 127;
                    C[(((size_t)(n >> 1) * 16 + b) * 128 + s) * 2 + (n & 1)] = v;
                }
            }
        }
    }
}

// ---------------- persistent encoder (unchanged from r9) ----------------

__global__ __launch_bounds__(256, 2) void enc_persist(
    const float* __restrict__ pre, const float* __restrict__ Whh,
    const float* __restrict__ h0zero, float* __restrict__ c,
    float* __restrict__ enc_out, int* bar) {
    __shared__ float4 red4[4 * 64 * 17];
    __shared__ float zred[256];
    const int bk = blockIdx.x;
    const int tid = threadIdx.x;
    const int wv = tid >> 6, lane = tid & 63;
    const int k0 = wv * 256 + lane * 4;

    float4 wr[2][4];
#pragma unroll
    for (int dd = 0; dd < 2; ++dd) {
        int d = (bk << 1) + dd;
#pragma unroll
        for (int g = 0; g < 4; ++g)
            wr[dd][g] = *(const float4*)(Whh + (size_t)(g * 1024 + d) * H_ + k0);
    }

    int ep = 0;
    for (int t = 0; t < 128; ++t) {
        const float* xsrc;
        size_t xstr;
        if (t == 0) { xsrc = h0zero; xstr = H_; }
        else { xsrc = enc_out + (size_t)(t - 1) * H_; xstr = (size_t)128 * H_; }

        float prz[8];
        if (tid < 16) {
            const float* pb = pre + ((size_t)t * 512 + bk) * 128 + tid * 8;
#pragma unroll
            for (int q = 0; q < 8; ++q) prz[q] = pb[q];
        }

        float hloc0 = 0.f, hloc1 = 0.f;
        for (int dd = 0; dd < 2; ++dd) {
            float4 part[16];
#pragma unroll
            for (int b = 0; b < 16; ++b) {
                float4 hv = *(const float4*)(xsrc + (size_t)b * xstr + k0);
                part[b].x = dot4(wr[dd][0], hv);
                part[b].y = dot4(wr[dd][1], hv);
                part[b].z = dot4(wr[dd][2], hv);
                part[b].w = dot4(wr[dd][3], hv);
            }
#pragma unroll
            for (int b = 0; b < 16; ++b) red4[(wv * 64 + lane) * 17 + b] = part[b];
            __syncthreads();
            {
                int v = tid & 63, wq = tid >> 6;
                const float* rf = (const float*)red4;
                float s = 0.f;
#pragma unroll 8
                for (int l = 0; l < 64; ++l) s += rf[(wq * 64 + l) * 68 + v];
                zred[wq * 64 + v] = s;
            }
            __syncthreads();
            if (tid < 16) {
                int b = tid;
                const int d = (bk << 1) + dd;
                float zz[4];
#pragma unroll
                for (int g = 0; g < 4; ++g) {
                    float s = zred[b * 4 + g] + zred[64 + b * 4 + g] +
                              zred[128 + b * 4 + g] + zred[192 + b * 4 + g];
                    zz[g] = s + prz[g * 2 + dd];
                }
                float co = c[b * H_ + d];
                float c2 = sigm(zz[1]) * co + sigm(zz[0]) * tanhf(zz[2]);
                float h2 = sigm(zz[3]) * tanhf(c2);
                c[b * H_ + d] = c2;
                if (dd == 0) hloc0 = h2; else hloc1 = h2;
            }
            __syncthreads();
        }
        if (tid < 16)
            pub2(&enc_out[((size_t)tid * 128 + t) * H_ + (bk << 1)], hloc0, hloc1);
        ++ep;
        gbar(bar, ep, bk);
    }
}

// ---------------- persistent decoder v2: LSTM | dist-scores | softmax+PE+a2 ----

__global__ __launch_bounds__(256, 2) void dec_persist(
    const float* __restrict__ pre, const float* __restrict__ Whh,
    const float* __restrict__ WihFull, const float* __restrict__ attn_W,
    const float* __restrict__ attn_b, const float* __restrict__ enc_out,
    const float* __restrict__ PE2,
    float* __restrict__ h_ring, float* __restrict__ a_ring,
    float* __restrict__ scores_ring, const float* __restrict__ a0zero,
    float* __restrict__ c, const int* __restrict__ mask2,
    u16* __restrict__ a2bf, int* bar) {
    __shared__ float4 red4[4 * 64 * 17];
    __shared__ float zred[256];
    __shared__ float ps2[2048];
    const int bk = blockIdx.x;
    const int tid = threadIdx.x;
    const int wv = tid >> 6, lane = tid & 63;
    const int kq = (wv & 1) * 512 + lane * 8;
    const bool isA = wv >= 2;

    // LSTM weights in regs
    float4 wr[2][4][2];
#pragma unroll
    for (int dd = 0; dd < 2; ++dd) {
        int d = (bk << 1) + dd;
#pragma unroll
        for (int g = 0; g < 4; ++g) {
            int j = g * 1024 + d;
            const float* wsrc = isA ? (WihFull + (size_t)j * 1536 + 512 + kq)
                                    : (Whh + (size_t)j * H_ + kq);
            wr[dd][g][0] = *(const float4*)(wsrc);
            wr[dd][g][1] = *(const float4*)(wsrc + 4);
        }
    }
    // a2 h-side weights: Wh[d][1024+ksl..], ksl = wv*256+lane*4
    const int ksl = wv * 256 + lane * 4;
    float4 wa2h[2];
#pragma unroll
    for (int dd = 0; dd < 2; ++dd)
        wa2h[dd] = *(const float4*)(attn_W + (size_t)((bk << 1) + dd) * 2048 + 1024 + ksl);

    int ep = 0;
    for (int t = 0; t < T1_; ++t) {
        const float* hsrc;
        size_t hstr;
        if (t == 0) { hsrc = enc_out + (size_t)127 * H_; hstr = (size_t)128 * H_; }
        else { hsrc = h_ring + (size_t)(t - 1) * B_ * H_; hstr = H_; }
        const float* asrc = (t == 0) ? a0zero : (a_ring + (size_t)(t - 1) * B_ * H_);
        float* hcur = h_ring + (size_t)t * B_ * H_;
        float* acur = a_ring + (size_t)t * B_ * H_;
        float* srow = scores_ring + (size_t)t * 2048;

        float prz[8];
        if (tid < 16) {
            const float* pb = pre + ((size_t)t * 512 + bk) * 128 + tid * 8;
#pragma unroll
            for (int q = 0; q < 8; ++q) prz[q] = pb[q];
        }

        // ---- phase 1: LSTM for my 2 d ----
        const float* xsrc1 = isA ? asrc : hsrc;
        const size_t xstr1 = isA ? (size_t)H_ : hstr;
        float hloc0 = 0.f, hloc1 = 0.f;
        for (int dd = 0; dd < 2; ++dd) {
            float4 part[16];
#pragma unroll
            for (int b = 0; b < 16; ++b) {
                float4 x0 = *(const float4*)(xsrc1 + (size_t)b * xstr1 + kq);
                float4 x1 = *(const float4*)(xsrc1 + (size_t)b * xstr1 + kq + 4);
                part[b].x = dot4(wr[dd][0][0], x0) + dot4(wr[dd][0][1], x1);
                part[b].y = dot4(wr[dd][1][0], x0) + dot4(wr[dd][1][1], x1);
                part[b].z = dot4(wr[dd][2][0], x0) + dot4(wr[dd][2][1], x1);
                part[b].w = dot4(wr[dd][3][0], x0) + dot4(wr[dd][3][1], x1);
            }
#pragma unroll
            for (int b = 0; b < 16; ++b) red4[(wv * 64 + lane) * 17 + b] = part[b];
            __syncthreads();
            {
                int v = tid & 63, wq = tid >> 6;
                const float* rf = (const float*)red4;
                float s = 0.f;
#pragma unroll 8
                for (int l = 0; l < 64; ++l) s += rf[(wq * 64 + l) * 68 + v];
                zred[wq * 64 + v] = s;
            }
            __syncthreads();
            if (tid < 16) {
                int b = tid;
                const int d = (bk << 1) + dd;
                float zz[4];
#pragma unroll
                for (int g = 0; g < 4; ++g) {
                    float s = zred[b * 4 + g] + zred[64 + b * 4 + g] +
                              zred[128 + b * 4 + g] + zred[192 + b * 4 + g];
                    zz[g] = s + prz[g * 2 + dd];
                }
                float co = c[b * H_ + d];
                float c2 = sigm(zz[1]) * co + sigm(zz[0]) * tanhf(zz[2]);
                float h2 = sigm(zz[3]) * tanhf(c2);
                c[b * H_ + d] = c2;
                if (dd == 0) hloc0 = h2; else hloc1 = h2;
            }
            __syncthreads();
        }
        if (tid < 16) pub2(&hcur[tid * H_ + (bk << 1)], hloc0, hloc1);
        ++ep;
        gbar(bar, ep, bk);

        // ---- phase 2: distributed scores (all 512 blocks; 1 s per wave) ----
        {
            const int sb = bk & 15;
            const int s = ((bk >> 4) << 2) + wv;  // 0..127
            const float* er = enc_out + ((size_t)sb * 128 + s) * H_;
            const float* hr = hcur + (size_t)sb * H_;
            const int kk = lane * 16;
            float sc = 0.f;
#pragma unroll
            for (int q = 0; q < 4; ++q) {
                float4 e = *(const float4*)(er + kk + q * 4);
                float4 h = *(const float4*)(hr + kk + q * 4);
                sc += dot4(e, h);
            }
#pragma unroll
            for (int off = 32; off; off >>= 1) sc += __shfl_xor(sc, off);
            if (lane == 0) {
                float val = (mask2[sb * 128 + s] == 1) ? NEGBIG : sc;
                atomicExch((unsigned*)&srow[sb * 128 + s], __float_as_uint(val));
            }
        }
        ++ep;
        gbar(bar, ep, bk);

        // ---- phase 3: softmax (redundant per block) + PE attn + Wh.h2 -> a2 ----
        {
            float4 s0 = *(const float4*)(srow + tid * 8);
            float4 s1 = *(const float4*)(srow + tid * 8 + 4);
            *(float4*)(ps2 + tid * 8) = s0;
            *(float4*)(ps2 + tid * 8 + 4) = s1;
        }
        __syncthreads();
        {
            const int b = tid >> 4, l16 = tid & 15;
            float* pr = ps2 + b * 128 + l16 * 8;
            float m8 = pr[0];
#pragma unroll
            for (int q = 1; q < 8; ++q) m8 = fmaxf(m8, pr[q]);
#pragma unroll
            for (int off = 8; off; off >>= 1) m8 = fmaxf(m8, __shfl_xor(m8, off, 16));
            float e[8], ssum = 0.f;
#pragma unroll
            for (int q = 0; q < 8; ++q) { e[q] = expf(pr[q] - m8); ssum += e[q]; }
#pragma unroll
            for (int off = 8; off; off >>= 1) ssum += __shfl_xor(ssum, off, 16);
            float inv = 1.f / ssum;
            // PE part: contiguous 16 floats per thread
            const float* pe = PE2 + (((size_t)bk * 16 + b) * 128 + l16 * 8) * 2;
            float pe0 = 0.f, pe1 = 0.f;
#pragma unroll
            for (int q = 0; q < 8; ++q) {
                float pq = e[q] * inv;
                pe0 += pq * pe[q * 2];
                pe1 += pq * pe[q * 2 + 1];
            }
#pragma unroll
            for (int off = 8; off; off >>= 1) {
                pe0 += __shfl_xor(pe0, off, 16);
                pe1 += __shfl_xor(pe1, off, 16);
            }
            if (l16 == 0) { zred[64 + b * 2] = pe0; zred[64 + b * 2 + 1] = pe1; }
        }
        float aloc0 = 0.f, aloc1 = 0.f;
        for (int dd = 0; dd < 2; ++dd) {
            float partA[16];
#pragma unroll
            for (int b = 0; b < 16; ++b) {
                float4 hv = *(const float4*)(hcur + (size_t)b * H_ + ksl);
                partA[b] = dot4(wa2h[dd], hv);
            }
#pragma unroll
            for (int q = 0; q < 4; ++q)
                red4[(wv * 64 + lane) * 17 + q] =
                    make_float4(partA[q * 4], partA[q * 4 + 1], partA[q * 4 + 2], partA[q * 4 + 3]);
            __syncthreads();
            if (tid < 64) {
                int v = tid & 15, wq = tid >> 4;
                const float* rf = (const float*)red4;
                float s = 0.f;
#pragma unroll 8
                for (int l = 0; l < 64; ++l) s += rf[(wq * 64 + l) * 68 + v];
                zred[wq * 16 + v] = s;
            }
            __syncthreads();
            if (tid < 16) {
                int b = tid;
                float v = zred[b] + zred[16 + b] + zred[32 + b] + zred[48 + b] +
                          zred[64 + b * 2 + dd] + attn_b[(bk << 1) + dd];
                v = tanhf(v);
                if (dd == 0) aloc0 = v; else aloc1 = v;
            }
            __syncthreads();
        }
        if (tid < 16) {
            pub2(&acur[tid * H_ + (bk << 1)], aloc0, aloc1);
            unsigned pk2 = (unsigned)f2bf(aloc0) | ((unsigned)f2bf(aloc1) << 16);
            *(unsigned*)&a2bf[((size_t)(t * 16 + tid)) * H_ + (bk << 1)] = pk2;
        }
        ++ep;
        gbar(bar, ep, bk);
    }
}

// ---------------- orchestration ----------------

extern "C" void kernel_launch(void* const* d_in, const int* in_sizes, int n_in,
                              void* d_out, int out_size, void* d_ws, size_t ws_size,
                              hipStream_t stream) {
    const int* in_tok = (const int*)d_in[0];
    const int* out_tok = (const int*)d_in[1];
    const int* mask = (const int*)d_in[2];
    const float* emb_in = (const float*)d_in[3];
    const float* emb_out = (const float*)d_in[4];
    const float* enc_Wih = (const float*)d_in[5];
    const float* enc_Whh = (const float*)d_in[6];
    const float* enc_bih = (const float*)d_in[7];
    const float* enc_bhh = (const float*)d_in[8];
    const float* dec_Wih = (const float*)d_in[9];
    const float* dec_Whh = (const float*)d_in[10];
    const float* dec_bih = (const float*)d_in[11];
    const float* dec_bhh = (const float*)d_in[12];
    const float* attn_W = (const float*)d_in[13];
    const float* attn_b = (const float*)d_in[14];
    const float* out_W = (const float*)d_in[15];
    const float* out_b = (const float*)d_in[16];
    float* out = (float*)d_out;

    char* p = (char*)d_ws;
    auto alloc = [&](size_t bytes) {
        char* r = p;
        p += (bytes + 255) & ~(size_t)255;
        return r;
    };
    u16* A_enc3 = (u16*)alloc((size_t)2048 * 1536 * 2);
    u16* A_dec3 = (u16*)alloc((size_t)2048 * 1536 * 2);
    u16* W_e3 = (u16*)alloc((size_t)4096 * 1536 * 2);
    u16* W_d3 = (u16*)alloc((size_t)4096 * 1536 * 2);
    u16* Wo = (u16*)alloc((size_t)32000 * 1024 * 2);
    float* enc_pre = (float*)alloc((size_t)2048 * 4096 * 4);
    float* dec_pre = (float*)alloc((size_t)2048 * 4096 * 4);
    float* enc_out = (float*)alloc((size_t)16 * 128 * 1024 * 4);
    u16* a2bf = (u16*)alloc((size_t)2048 * 1024 * 2);
    u16* A3pe = (u16*)alloc((size_t)2048 * 3072 * 2);
    u16* Wpe3 = (u16*)alloc((size_t)1024 * 3072 * 2);
    float* PE2 = (float*)alloc((size_t)1024 * 16 * 128 * 4);
    float* h0 = (float*)alloc(16 * 1024 * 4);
    float* c = (float*)alloc(16 * 1024 * 4);
    float* a0 = (float*)alloc(16 * 1024 * 4);
    int* barE = (int*)alloc(4096 * 4);
    int* barD = (int*)alloc(4096 * 4);
    int* mask2 = (int*)alloc(16 * 128 * 4);

    // write-once rings aliased onto dead staging buffers (A_enc3..W_e3 span)
    float* h_ring = (float*)A_enc3;
    float* a_ring = h_ring + (size_t)128 * B_ * H_;
    float* scores_ring = a_ring + (size_t)128 * B_ * H_;

    init_k<<<48, 256, 0, stream>>>(h0, barE, mask, mask2);

    split3_rows_k<<<4096, 128, 0, stream>>>(enc_Wih, 512, W_e3, 4096, 1024, 512);
    split3_rows_k<<<4096, 128, 0, stream>>>(dec_Wih, 1536, W_d3, 4096, 1024, 512);
    split3_1024_k<<<1024, 256, 0, stream>>>(attn_W, 2048, Wpe3, 2048, 1024);  // B-side
    f32_to_bf16_k<<<32000, 256, 0, stream>>>(out_W, Wo, 32000 * 1024 / 4);
    gather_split_k<<<2048, 128, 0, stream>>>(in_tok, emb_in, A_enc3, 2048);
    gather_split_k<<<2032, 128, 0, stream>>>(out_tok, emb_out, A_dec3, 2032);

    gemm_bt<2><<<dim3(16, 32), 256, 0, stream>>>(A_enc3, W_e3, enc_pre, enc_bih, enc_bhh,
                                                 2048, 4096, 1536);
    gemm_bt<2><<<dim3(16, 32), 256, 0, stream>>>(A_dec3, W_d3, dec_pre, dec_bih, dec_bhh,
                                                 2048, 4096, 1536);

    enc_persist<<<512, 256, 0, stream>>>(enc_pre, enc_Whh, h0, c, enc_out, barE);

    // PE precompute: PE[b,s,d] = enc_out[b,s,:] . attn_W[d, :1024] (split-fp32)
    split3_1024_k<<<2048, 256, 0, stream>>>(enc_out, 1024, A3pe, 1024, 2048);  // A-side
    gemm_bt<3><<<dim3(16, 8), 256, 0, stream>>>(A3pe, Wpe3, PE2, nullptr, nullptr,
                                                2048, 1024, 3072);

    dec_persist<<<512, 256, 0, stream>>>(dec_pre, dec_Whh, dec_Wih, attn_W, attn_b,
                                         enc_out, PE2, h_ring, a_ring, scores_ring,
                                         a0, c, mask2, a2bf, barD);

    gemm_bt<1><<<dim3(16, 250), 256, 0, stream>>>(a2bf, Wo, out, out_b, nullptr,
                                                  2048, 32000, 1024);
}

// Round 11
// 4447.787 us; speedup vs baseline: 3.0545x; 1.0433x over previous
//
#include <hip/hip_runtime.h>
#include <hip/hip_bf16.h>
#include <stdint.h>

typedef unsigned short u16;
typedef unsigned long long u64;
typedef __bf16 bf16x8v __attribute__((ext_vector_type(8)));
typedef float f32x4 __attribute__((ext_vector_type(4)));

#define B_ 16
#define S_ 128
#define T1_ 127
#define E_ 512
#define H_ 1024
#define H4_ 4096
#define V_ 32000
#define NEGBIG -1e10f
#define NBLK 512

__device__ __forceinline__ u16 f2bf(float f) {
    union { float f; unsigned u; } v; v.f = f;
    unsigned u = v.u;
    unsigned r = (u + 0x7fffu + ((u >> 16) & 1u)) >> 16;
    return (u16)r;
}
__device__ __forceinline__ float bf2f(u16 h) {
    union { unsigned u; float f; } v; v.u = ((unsigned)h) << 16;
    return v.f;
}
__device__ __forceinline__ float sigm(float x) { return 1.f / (1.f + expf(-x)); }
__device__ __forceinline__ float dot4(float4 a, float4 b) {
    return a.x * b.x + a.y * b.y + a.z * b.z + a.w * b.w;
}
__device__ __forceinline__ void pub2(float* p, float v0, float v1) {
    union { float f[2]; u64 u; } pk;
    pk.f[0] = v0; pk.f[1] = v1;
    atomicExch((u64*)p, pk.u);
}

// ---- grid barrier v6: SPLIT-PHASE tournament (proven v5 mechanics) ----
// arrive: drain own stores, 3-level RMW tree, winner writes 8 release lines.
// wait: system-scope relaxed load poll (L2-bypass, no fences).
// Between arrive and wait, blocks may do work that depends only on data
// synced at an EARLIER barrier (fuzzy barrier — hides RTT behind work).
__device__ __forceinline__ void gbar_arrive(int* bar, int ep, int bk) {
    asm volatile("s_waitcnt vmcnt(0) lgkmcnt(0)" ::: "memory");
    __syncthreads();
    if (threadIdx.x == 0) {
        const int g1 = bk & 63, g2 = g1 >> 3;
        int old = atomicAdd(&bar[g1 * 16], 1);
        if (old == ep * 8 - 1) {
            int old2 = atomicAdd(&bar[1024 + g2 * 16], 1);
            if (old2 == ep * 8 - 1) {
                int old3 = atomicAdd(&bar[1152], 1);
                if (old3 == ep * 8 - 1) {
#pragma unroll
                    for (int j = 0; j < 8; ++j) atomicExch(&bar[1216 + j * 16], ep);
                }
            }
        }
    }
}
__device__ __forceinline__ void gbar_wait(int* bar, int ep, int bk) {
    if (threadIdx.x == 0) {
        while (__hip_atomic_load(&bar[1216 + (bk & 7) * 16], __ATOMIC_RELAXED,
                                 __HIP_MEMORY_SCOPE_SYSTEM) < ep)
            __builtin_amdgcn_s_sleep(2);
    }
    __syncthreads();
}

// ---------------- converts / gathers ----------------

__global__ __launch_bounds__(256) void f32_to_bf16_k(const float* __restrict__ src,
                                                     u16* __restrict__ dst, int n4) {
    int idx = blockIdx.x * 256 + threadIdx.x;
    if (idx >= n4) return;
    float4 v = ((const float4*)src)[idx];
    unsigned lo = (unsigned)f2bf(v.x) | ((unsigned)f2bf(v.y) << 16);
    unsigned hi = (unsigned)f2bf(v.z) | ((unsigned)f2bf(v.w) << 16);
    uint2 pk; pk.x = lo; pk.y = hi;
    *(uint2*)(dst + (size_t)idx * 4) = pk;
}

// 512-wide row -> 1536-wide split row (128 threads)
__global__ __launch_bounds__(128) void split3_rows_k(const float* __restrict__ src,
                                                     int srcStride,
                                                     u16* __restrict__ dst, int nrows,
                                                     int offH2, int offLo) {
    int j = blockIdx.x;
    if (j >= nrows) return;
    int tid = threadIdx.x;
    float4 v = *(const float4*)(src + (size_t)j * srcStride + tid * 4);
    u16 h0 = f2bf(v.x), h1 = f2bf(v.y), h2 = f2bf(v.z), h3 = f2bf(v.w);
    u16 l0 = f2bf(v.x - bf2f(h0)), l1 = f2bf(v.y - bf2f(h1));
    u16 l2 = f2bf(v.z - bf2f(h2)), l3 = f2bf(v.w - bf2f(h3));
    uint2 ph; ph.x = (unsigned)h0 | ((unsigned)h1 << 16); ph.y = (unsigned)h2 | ((unsigned)h3 << 16);
    uint2 pl; pl.x = (unsigned)l0 | ((unsigned)l1 << 16); pl.y = (unsigned)l2 | ((unsigned)l3 << 16);
    u16* base = dst + (size_t)j * 1536 + tid * 4;
    *(uint2*)(base) = ph;
    *(uint2*)(base + offH2) = ph;
    *(uint2*)(base + offLo) = pl;
}

// 1024-wide row -> 3072-wide split row (256 threads)
__global__ __launch_bounds__(256) void split3_1024_k(const float* __restrict__ src,
                                                     int srcStride,
                                                     u16* __restrict__ dst,
                                                     int offH2, int offLo) {
    int j = blockIdx.x, tid = threadIdx.x;
    float4 v = *(const float4*)(src + (size_t)j * srcStride + tid * 4);
    u16 h0 = f2bf(v.x), h1 = f2bf(v.y), h2 = f2bf(v.z), h3 = f2bf(v.w);
    u16 l0 = f2bf(v.x - bf2f(h0)), l1 = f2bf(v.y - bf2f(h1));
    u16 l2 = f2bf(v.z - bf2f(h2)), l3 = f2bf(v.w - bf2f(h3));
    uint2 ph; ph.x = (unsigned)h0 | ((unsigned)h1 << 16); ph.y = (unsigned)h2 | ((unsigned)h3 << 16);
    uint2 pl; pl.x = (unsigned)l0 | ((unsigned)l1 << 16); pl.y = (unsigned)l2 | ((unsigned)l3 << 16);
    u16* base = dst + (size_t)j * 3072 + tid * 4;
    *(uint2*)(base) = ph;
    *(uint2*)(base + offH2) = ph;
    *(uint2*)(base + offLo) = pl;
}

__global__ __launch_bounds__(128) void gather_split_k(const int* __restrict__ toks,
                                                      const float* __restrict__ emb,
                                                      u16* __restrict__ A, int nrows) {
    int m = blockIdx.x;
    if (m >= nrows) return;
    int tIdx = m >> 4, b = m & 15;
    int tok = toks[b * 128 + tIdx];
    int tid = threadIdx.x;
    float4 v = *(const float4*)(emb + (size_t)tok * E_ + tid * 4);
    u16 h0 = f2bf(v.x), h1 = f2bf(v.y), h2 = f2bf(v.z), h3 = f2bf(v.w);
    u16 l0 = f2bf(v.x - bf2f(h0)), l1 = f2bf(v.y - bf2f(h1));
    u16 l2 = f2bf(v.z - bf2f(h2)), l3 = f2bf(v.w - bf2f(h3));
    uint2 ph; ph.x = (unsigned)h0 | ((unsigned)h1 << 16); ph.y = (unsigned)h2 | ((unsigned)h3 << 16);
    uint2 pl; pl.x = (unsigned)l0 | ((unsigned)l1 << 16); pl.y = (unsigned)l2 | ((unsigned)l3 << 16);
    u16* base = A + (size_t)m * 1536 + tid * 4;
    *(uint2*)(base) = ph;
    *(uint2*)(base + 512) = ph;
    *(uint2*)(base + 1024) = pl;
}

// zero state (h0|c|a0) + barrier arrays + mask2
__global__ __launch_bounds__(256) void init_k(float* __restrict__ zero1,
                                              int* __restrict__ zero2,
                                              const int* __restrict__ mask,
                                              int* __restrict__ mask2) {
    int idx = blockIdx.x * 256 + threadIdx.x;
    float4 z = {0.f, 0.f, 0.f, 0.f};
    if (idx < 12288) ((float4*)zero1)[idx] = z;
    if (idx < 2048) { int4 zi = {0, 0, 0, 0}; ((int4*)zero2)[idx] = zi; }
    if (blockIdx.x == 0 && threadIdx.x < 16) {
        int b = threadIdx.x;
        int first0 = 128;
        for (int s = 0; s < 128; ++s) {
            if (mask[b * 128 + s] == 0) { first0 = s; break; }
        }
        if (first0 == 128) first0 = 0;
        int len = first0 - 1;
        int ix = (len < 0) ? 127 : len;
        for (int s = 0; s < 128; ++s) mask2[b * 128 + s] = mask[b * 128 + s];
        mask2[b * 128 + ix] = 0;
    }
}

// ---------------- bf16 MFMA GEMM ----------------
// MODE 1: logits. MODE 2: pre2 [t][d>>1][b][g][d&1]. MODE 3: PE2 [d>>1][b][s][d&1].

#define GLD_LDS(g, l) \
    __builtin_amdgcn_global_load_lds((const __attribute__((address_space(1))) void*)(g), \
                                     (__attribute__((address_space(3))) void*)(l), 16, 0, 0)

template <int MODE>
__global__ __launch_bounds__(256) void gemm_bt(const u16* __restrict__ A,
                                               const u16* __restrict__ Bt,
                                               float* __restrict__ C,
                                               const float* __restrict__ bias1,
                                               const float* __restrict__ bias2,
                                               int M, int N, int K) {
    __shared__ u16 As[128 * 32];
    __shared__ u16 Bs[128 * 32];
    const int tid = threadIdx.x;
    const int bm = blockIdx.x, bn = blockIdx.y;
    const int lane = tid & 63, w = tid >> 6;
    const int wm = (w >> 1) * 64, wn = (w & 1) * 64;
    f32x4 acc[4][4] = {};

    const int r0 = tid >> 2;
    const int c0 = (tid & 3) * 8;
    const u16* ga0 = A + (size_t)(bm * 128 + r0) * K + c0;
    const u16* ga1 = A + (size_t)(bm * 128 + 64 + r0) * K + c0;
    const u16* gb0 = Bt + (size_t)(bn * 128 + r0) * K + c0;
    const u16* gb1 = Bt + (size_t)(bn * 128 + 64 + r0) * K + c0;
    u16* lA0 = As + tid * 8;
    u16* lA1 = As + 2048 + tid * 8;
    u16* lB0 = Bs + tid * 8;
    u16* lB1 = Bs + 2048 + tid * 8;

    const int fl = lane & 15, kg = lane >> 4;

    for (int k0 = 0; k0 < K; k0 += 32) {
        __syncthreads();
        GLD_LDS(ga0 + k0, lA0);
        GLD_LDS(ga1 + k0, lA1);
        GLD_LDS(gb0 + k0, lB0);
        GLD_LDS(gb1 + k0, lB1);
        __syncthreads();
        bf16x8v af[4], bfv[4];
#pragma unroll
        for (int i = 0; i < 4; ++i)
            af[i] = *(const bf16x8v*)(As + (wm + i * 16 + fl) * 32 + kg * 8);
#pragma unroll
        for (int j = 0; j < 4; ++j)
            bfv[j] = *(const bf16x8v*)(Bs + (wn + j * 16 + fl) * 32 + kg * 8);
#pragma unroll
        for (int i = 0; i < 4; ++i)
#pragma unroll
            for (int j = 0; j < 4; ++j)
                acc[i][j] = __builtin_amdgcn_mfma_f32_16x16x32_bf16(af[i], bfv[j], acc[i][j], 0, 0, 0);
    }

    const int coll = lane & 15;
    const int rowb = (lane >> 4) * 4;
#pragma unroll
    for (int i = 0; i < 4; ++i) {
#pragma unroll
        for (int j = 0; j < 4; ++j) {
#pragma unroll
            for (int r = 0; r < 4; ++r) {
                int m = bm * 128 + wm + i * 16 + rowb + r;
                int n = bn * 128 + wn + j * 16 + coll;
                float v = acc[i][j][r];
                if (MODE == 1) {
                    int tt = m >> 4, bb = m & 15;
                    if (tt < T1_) C[((size_t)bb * T1_ + tt) * V_ + n] = v + bias1[n];
                } else if (MODE == 2) {
                    if (m < M) {
                        int tt = m >> 4, bb = m & 15;
                        int g = n >> 10, d = n & 1023;
                        C[(((size_t)tt * 512 + (d >> 1)) * 16 + bb) * 8 + g * 2 +
                          (d & 1)] = v + bias1[n] + bias2[n];
                    }
                } else {  // MODE 3: PE2[d>>1][b][s][d&1]; m = b*128+s
                    int b = m >> 7, s = m & 127;
                    C[(((size_t)(n >> 1) * 16 + b) * 128 + s) * 2 + (n & 1)] = v;
                }
            }
        }
    }
}

// ---------------- persistent encoder (split-phase barrier + prz dbuf) ----

__global__ __launch_bounds__(256, 2) void enc_persist(
    const float* __restrict__ pre, const float* __restrict__ Whh,
    const float* __restrict__ h0zero, float* __restrict__ c,
    float* __restrict__ enc_out, int* bar) {
    __shared__ float4 red4[4 * 64 * 17];
    __shared__ float zred[256];
    const int bk = blockIdx.x;
    const int tid = threadIdx.x;
    const int wv = tid >> 6, lane = tid & 63;
    const int k0 = wv * 256 + lane * 4;

    float4 wr[2][4];
#pragma unroll
    for (int dd = 0; dd < 2; ++dd) {
        int d = (bk << 1) + dd;
#pragma unroll
        for (int g = 0; g < 4; ++g)
            wr[dd][g] = *(const float4*)(Whh + (size_t)(g * 1024 + d) * H_ + k0);
    }

    float prz[8];
    if (tid < 16) {
        const float* pb = pre + ((size_t)0 * 512 + bk) * 128 + tid * 8;
#pragma unroll
        for (int q = 0; q < 8; ++q) prz[q] = pb[q];
    }

    int ep = 0;
    for (int t = 0; t < 128; ++t) {
        const float* xsrc;
        size_t xstr;
        if (t == 0) { xsrc = h0zero; xstr = H_; }
        else { xsrc = enc_out + (size_t)(t - 1) * H_; xstr = (size_t)128 * H_; }

        float hloc0 = 0.f, hloc1 = 0.f;
        for (int dd = 0; dd < 2; ++dd) {
            float4 part[16];
#pragma unroll
            for (int b = 0; b < 16; ++b) {
                float4 hv = *(const float4*)(xsrc + (size_t)b * xstr + k0);
                part[b].x = dot4(wr[dd][0], hv);
                part[b].y = dot4(wr[dd][1], hv);
                part[b].z = dot4(wr[dd][2], hv);
                part[b].w = dot4(wr[dd][3], hv);
            }
#pragma unroll
            for (int b = 0; b < 16; ++b) red4[(wv * 64 + lane) * 17 + b] = part[b];
            __syncthreads();
            {
                int v = tid & 63, wq = tid >> 6;
                const float* rf = (const float*)red4;
                float s = 0.f;
#pragma unroll 8
                for (int l = 0; l < 64; ++l) s += rf[(wq * 64 + l) * 68 + v];
                zred[wq * 64 + v] = s;
            }
            __syncthreads();
            if (tid < 16) {
                int b = tid;
                const int d = (bk << 1) + dd;
                float zz[4];
#pragma unroll
                for (int g = 0; g < 4; ++g) {
                    float s = zred[b * 4 + g] + zred[64 + b * 4 + g] +
                              zred[128 + b * 4 + g] + zred[192 + b * 4 + g];
                    zz[g] = s + prz[g * 2 + dd];
                }
                float co = c[b * H_ + d];
                float c2 = sigm(zz[1]) * co + sigm(zz[0]) * tanhf(zz[2]);
                float h2 = sigm(zz[3]) * tanhf(c2);
                c[b * H_ + d] = c2;
                if (dd == 0) hloc0 = h2; else hloc1 = h2;
            }
            __syncthreads();
        }
        if (tid < 16)
            pub2(&enc_out[((size_t)tid * 128 + t) * H_ + (bk << 1)], hloc0, hloc1);
        ++ep;
        gbar_arrive(bar, ep, bk);
        // window: prefetch next step's gate pre-activations (read-only data)
        float przn[8];
        if (tid < 16 && t + 1 < 128) {
            const float* pb = pre + ((size_t)(t + 1) * 512 + bk) * 128 + tid * 8;
#pragma unroll
            for (int q = 0; q < 8; ++q) przn[q] = pb[q];
        }
        gbar_wait(bar, ep, bk);
        if (tid < 16 && t + 1 < 128) {
#pragma unroll
            for (int q = 0; q < 8; ++q) prz[q] = przn[q];
        }
    }
}

// ---------------- persistent decoder: split-phase, hoisted window work ----

__global__ __launch_bounds__(256, 2) void dec_persist(
    const float* __restrict__ pre, const float* __restrict__ Whh,
    const float* __restrict__ WihFull, const float* __restrict__ attn_W,
    const float* __restrict__ attn_b, const float* __restrict__ enc_out,
    const float* __restrict__ PE2,
    float* __restrict__ h_ring, float* __restrict__ a_ring,
    float* __restrict__ scores_ring, const float* __restrict__ a0zero,
    float* __restrict__ c, const int* __restrict__ mask2,
    u16* __restrict__ a2bf, int* bar) {
    __shared__ float4 red4[4 * 64 * 17];
    __shared__ float zred[256];
    __shared__ float ps2[2048];
    const int bk = blockIdx.x;
    const int tid = threadIdx.x;
    const int wv = tid >> 6, lane = tid & 63;
    const int kq = (wv & 1) * 512 + lane * 8;
    const bool isA = wv >= 2;

    float4 wr[2][4][2];
#pragma unroll
    for (int dd = 0; dd < 2; ++dd) {
        int d = (bk << 1) + dd;
#pragma unroll
        for (int g = 0; g < 4; ++g) {
            int j = g * 1024 + d;
            const float* wsrc = isA ? (WihFull + (size_t)j * 1536 + 512 + kq)
                                    : (Whh + (size_t)j * H_ + kq);
            wr[dd][g][0] = *(const float4*)(wsrc);
            wr[dd][g][1] = *(const float4*)(wsrc + 4);
        }
    }
    const int ksl = wv * 256 + lane * 4;
    float4 wa2h[2];
#pragma unroll
    for (int dd = 0; dd < 2; ++dd)
        wa2h[dd] = *(const float4*)(attn_W + (size_t)((bk << 1) + dd) * 2048 + 1024 + ksl);

    const int sb = bk & 15;             // score batch for phase 2
    const int ss = ((bk >> 4) << 2) + wv;  // score s-index for phase 2

    int ep = 0;
    for (int t = 0; t < T1_; ++t) {
        const float* hsrc;
        size_t hstr;
        if (t == 0) { hsrc = enc_out + (size_t)127 * H_; hstr = (size_t)128 * H_; }
        else { hsrc = h_ring + (size_t)(t - 1) * B_ * H_; hstr = H_; }
        const float* asrc = (t == 0) ? a0zero : (a_ring + (size_t)(t - 1) * B_ * H_);
        float* hcur = h_ring + (size_t)t * B_ * H_;
        float* acur = a_ring + (size_t)t * B_ * H_;
        float* srow = scores_ring + (size_t)t * 2048;

        float prz[8];
        if (tid < 16) {
            const float* pb = pre + ((size_t)t * 512 + bk) * 128 + tid * 8;
#pragma unroll
            for (int q = 0; q < 8; ++q) prz[q] = pb[q];
        }

        // ---- phase 1: LSTM for my 2 d ----
        const float* xsrc1 = isA ? asrc : hsrc;
        const size_t xstr1 = isA ? (size_t)H_ : hstr;
        float hloc0 = 0.f, hloc1 = 0.f;
        for (int dd = 0; dd < 2; ++dd) {
            float4 part[16];
#pragma unroll
            for (int b = 0; b < 16; ++b) {
                float4 x0 = *(const float4*)(xsrc1 + (size_t)b * xstr1 + kq);
                float4 x1 = *(const float4*)(xsrc1 + (size_t)b * xstr1 + kq + 4);
                part[b].x = dot4(wr[dd][0][0], x0) + dot4(wr[dd][0][1], x1);
                part[b].y = dot4(wr[dd][1][0], x0) + dot4(wr[dd][1][1], x1);
                part[b].z = dot4(wr[dd][2][0], x0) + dot4(wr[dd][2][1], x1);
                part[b].w = dot4(wr[dd][3][0], x0) + dot4(wr[dd][3][1], x1);
            }
#pragma unroll
            for (int b = 0; b < 16; ++b) red4[(wv * 64 + lane) * 17 + b] = part[b];
            __syncthreads();
            {
                int v = tid & 63, wq = tid >> 6;
                const float* rf = (const float*)red4;
                float s = 0.f;
#pragma unroll 8
                for (int l = 0; l < 64; ++l) s += rf[(wq * 64 + l) * 68 + v];
                zred[wq * 64 + v] = s;
            }
            __syncthreads();
            if (tid < 16) {
                int b = tid;
                const int d = (bk << 1) + dd;
                float zz[4];
#pragma unroll
                for (int g = 0; g < 4; ++g) {
                    float s = zred[b * 4 + g] + zred[64 + b * 4 + g] +
                              zred[128 + b * 4 + g] + zred[192 + b * 4 + g];
                    zz[g] = s + prz[g * 2 + dd];
                }
                float co = c[b * H_ + d];
                float c2 = sigm(zz[1]) * co + sigm(zz[0]) * tanhf(zz[2]);
                float h2 = sigm(zz[3]) * tanhf(c2);
                c[b * H_ + d] = c2;
                if (dd == 0) hloc0 = h2; else hloc1 = h2;
            }
            __syncthreads();
        }
        if (tid < 16) pub2(&hcur[tid * H_ + (bk << 1)], hloc0, hloc1);
        ++ep;
        gbar_arrive(bar, ep, bk);
        // B1 window: prefetch enc_out row for phase 2 (read-only since encoder)
        float4 er4[4];
        {
            const float* er = enc_out + ((size_t)sb * 128 + ss) * H_ + lane * 16;
#pragma unroll
            for (int q = 0; q < 4; ++q) er4[q] = *(const float4*)(er + q * 4);
        }
        gbar_wait(bar, ep, bk);

        // ---- phase 2: distributed scores (1 s per wave) ----
        {
            const float* hr = hcur + (size_t)sb * H_ + lane * 16;
            float sc = 0.f;
#pragma unroll
            for (int q = 0; q < 4; ++q) sc += dot4(er4[q], *(const float4*)(hr + q * 4));
#pragma unroll
            for (int off = 32; off; off >>= 1) sc += __shfl_xor(sc, off);
            if (lane == 0) {
                float val = (mask2[sb * 128 + ss] == 1) ? NEGBIG : sc;
                atomicExch((unsigned*)&srow[sb * 128 + ss], __float_as_uint(val));
            }
        }
        ++ep;
        gbar_arrive(bar, ep, bk);
        // B2 window: Wh.h2 partials for a2 (h2 synced at B1 — independent of B2)
        float partA[2][16];
#pragma unroll
        for (int dd = 0; dd < 2; ++dd)
#pragma unroll
            for (int b = 0; b < 16; ++b)
                partA[dd][b] = dot4(wa2h[dd], *(const float4*)(hcur + (size_t)b * H_ + ksl));
        gbar_wait(bar, ep, bk);

        // ---- phase 3: softmax (redundant) + PE attn + reduce -> a2 ----
        {
            float4 s0 = *(const float4*)(srow + tid * 8);
            float4 s1 = *(const float4*)(srow + tid * 8 + 4);
            *(float4*)(ps2 + tid * 8) = s0;
            *(float4*)(ps2 + tid * 8 + 4) = s1;
        }
        __syncthreads();
        {
            const int b = tid >> 4, l16 = tid & 15;
            float* pr = ps2 + b * 128 + l16 * 8;
            float m8 = pr[0];
#pragma unroll
            for (int q = 1; q < 8; ++q) m8 = fmaxf(m8, pr[q]);
#pragma unroll
            for (int off = 8; off; off >>= 1) m8 = fmaxf(m8, __shfl_xor(m8, off, 16));
            float e[8], ssum = 0.f;
#pragma unroll
            for (int q = 0; q < 8; ++q) { e[q] = expf(pr[q] - m8); ssum += e[q]; }
#pragma unroll
            for (int off = 8; off; off >>= 1) ssum += __shfl_xor(ssum, off, 16);
            float inv = 1.f / ssum;
            const float* pe = PE2 + (((size_t)bk * 16 + b) * 128 + l16 * 8) * 2;
            float pe0 = 0.f, pe1 = 0.f;
#pragma unroll
            for (int q = 0; q < 8; ++q) {
                float pq = e[q] * inv;
                pe0 += pq * pe[q * 2];
                pe1 += pq * pe[q * 2 + 1];
            }
#pragma unroll
            for (int off = 8; off; off >>= 1) {
                pe0 += __shfl_xor(pe0, off, 16);
                pe1 += __shfl_xor(pe1, off, 16);
            }
            if (l16 == 0) { zred[64 + b * 2] = pe0; zred[64 + b * 2 + 1] = pe1; }
        }
        float aloc0 = 0.f, aloc1 = 0.f;
        for (int dd = 0; dd < 2; ++dd) {
#pragma unroll
            for (int q = 0; q < 4; ++q)
                red4[(wv * 64 + lane) * 17 + q] =
                    make_float4(partA[dd][q * 4], partA[dd][q * 4 + 1],
                                partA[dd][q * 4 + 2], partA[dd][q * 4 + 3]);
            __syncthreads();
            if (tid < 64) {
                int v = tid & 15, wq = tid >> 4;
                const float* rf = (const float*)red4;
                float s = 0.f;
#pragma unroll 8
                for (int l = 0; l < 64; ++l) s += rf[(wq * 64 + l) * 68 + v];
                zred[wq * 16 + v] = s;
            }
            __syncthreads();
            if (tid < 16) {
                int b = tid;
                float v = zred[b] + zred[16 + b] + zred[32 + b] + zred[48 + b] +
                          zred[64 + b * 2 + dd] + attn_b[(bk << 1) + dd];
                v = tanhf(v);
                if (dd == 0) aloc0 = v; else aloc1 = v;
            }
            __syncthreads();
        }
        if (tid < 16) {
            pub2(&acur[tid * H_ + (bk << 1)], aloc0, aloc1);
            unsigned pk2 = (unsigned)f2bf(aloc0) | ((unsigned)f2bf(aloc1) << 16);
            *(unsigned*)&a2bf[((size_t)(t * 16 + tid)) * H_ + (bk << 1)] = pk2;
        }
        ++ep;
        gbar_arrive(bar, ep, bk);
        gbar_wait(bar, ep, bk);
    }
}

// ---------------- orchestration ----------------

extern "C" void kernel_launch(void* const* d_in, const int* in_sizes, int n_in,
                              void* d_out, int out_size, void* d_ws, size_t ws_size,
                              hipStream_t stream) {
    const int* in_tok = (const int*)d_in[0];
    const int* out_tok = (const int*)d_in[1];
    const int* mask = (const int*)d_in[2];
    const float* emb_in = (const float*)d_in[3];
    const float* emb_out = (const float*)d_in[4];
    const float* enc_Wih = (const float*)d_in[5];
    const float* enc_Whh = (const float*)d_in[6];
    const float* enc_bih = (const float*)d_in[7];
    const float* enc_bhh = (const float*)d_in[8];
    const float* dec_Wih = (const float*)d_in[9];
    const float* dec_Whh = (const float*)d_in[10];
    const float* dec_bih = (const float*)d_in[11];
    const float* dec_bhh = (const float*)d_in[12];
    const float* attn_W = (const float*)d_in[13];
    const float* attn_b = (const float*)d_in[14];
    const float* out_W = (const float*)d_in[15];
    const float* out_b = (const float*)d_in[16];
    float* out = (float*)d_out;

    char* p = (char*)d_ws;
    auto alloc = [&](size_t bytes) {
        char* r = p;
        p += (bytes + 255) & ~(size_t)255;
        return r;
    };
    u16* A_enc3 = (u16*)alloc((size_t)2048 * 1536 * 2);
    u16* A_dec3 = (u16*)alloc((size_t)2048 * 1536 * 2);
    u16* W_e3 = (u16*)alloc((size_t)4096 * 1536 * 2);
    u16* W_d3 = (u16*)alloc((size_t)4096 * 1536 * 2);
    u16* Wo = (u16*)alloc((size_t)32000 * 1024 * 2);
    float* enc_pre = (float*)alloc((size_t)2048 * 4096 * 4);
    float* dec_pre = (float*)alloc((size_t)2048 * 4096 * 4);
    float* enc_out = (float*)alloc((size_t)16 * 128 * 1024 * 4);
    u16* a2bf = (u16*)alloc((size_t)2048 * 1024 * 2);
    u16* A3pe = (u16*)alloc((size_t)2048 * 3072 * 2);
    u16* Wpe3 = (u16*)alloc((size_t)1024 * 3072 * 2);
    float* PE2 = (float*)alloc((size_t)1024 * 16 * 128 * 4);
    float* h0 = (float*)alloc(16 * 1024 * 4);
    float* c = (float*)alloc(16 * 1024 * 4);
    float* a0 = (float*)alloc(16 * 1024 * 4);
    int* barE = (int*)alloc(4096 * 4);
    int* barD = (int*)alloc(4096 * 4);
    int* mask2 = (int*)alloc(16 * 128 * 4);

    // write-once rings aliased onto dead staging buffers (A_enc3..W_e3 span)
    float* h_ring = (float*)A_enc3;
    float* a_ring = h_ring + (size_t)128 * B_ * H_;
    float* scores_ring = a_ring + (size_t)128 * B_ * H_;

    init_k<<<48, 256, 0, stream>>>(h0, barE, mask, mask2);

    split3_rows_k<<<4096, 128, 0, stream>>>(enc_Wih, 512, W_e3, 4096, 1024, 512);
    split3_rows_k<<<4096, 128, 0, stream>>>(dec_Wih, 1536, W_d3, 4096, 1024, 512);
    split3_1024_k<<<1024, 256, 0, stream>>>(attn_W, 2048, Wpe3, 2048, 1024);  // B-side
    f32_to_bf16_k<<<32000, 256, 0, stream>>>(out_W, Wo, 32000 * 1024 / 4);
    gather_split_k<<<2048, 128, 0, stream>>>(in_tok, emb_in, A_enc3, 2048);
    gather_split_k<<<2032, 128, 0, stream>>>(out_tok, emb_out, A_dec3, 2032);

    gemm_bt<2><<<dim3(16, 32), 256, 0, stream>>>(A_enc3, W_e3, enc_pre, enc_bih, enc_bhh,
                                                 2048, 4096, 1536);
    gemm_bt<2><<<dim3(16, 32), 256, 0, stream>>>(A_dec3, W_d3, dec_pre, dec_bih, dec_bhh,
                                                 2048, 4096, 1536);

    enc_persist<<<512, 256, 0, stream>>>(enc_pre, enc_Whh, h0, c, enc_out, barE);

    // PE precompute: PE[b,s,d] = enc_out[b,s,:] . attn_W[d, :1024] (split-fp32)
    split3_1024_k<<<2048, 256, 0, stream>>>(enc_out, 1024, A3pe, 1024, 2048);  // A-side
    gemm_bt<3><<<dim3(16, 8), 256, 0, stream>>>(A3pe, Wpe3, PE2, nullptr, nullptr,
                                                2048, 1024, 3072);

    dec_persist<<<512, 256, 0, stream>>>(dec_pre, dec_Whh, dec_Wih, attn_W, attn_b,
                                         enc_out, PE2, h_ring, a_ring, scores_ring,
                                         a0, c, mask2, a2bf, barD);

    gemm_bt<1><<<dim3(16, 250), 256, 0, stream>>>(a2bf, Wo, out, out_b, nullptr,
                                                  2048, 32000, 1024);
}